// Round 4
// baseline (969.771 us; speedup 1.0000x reference)
//
#include <hip/hip_runtime.h>
#include <math.h>

#define N0c   16
#define NAt   96
#define ORIG  92
#define Fc    64
#define Kc    41
#define Hc    128
#define NCc   3
#define C2    128   // 2F
#define EPSBN 1e-5f
#define JG    4
#define JPW   (NAt / JG)
#define NREP  32    // atomic replica slots
#define SRL_STRIDE 12288   // per-layer replica block
#define AROW  72    // LDS A row stride (ushorts)
#define WFRAG 16384 // ushorts per layer in W3F (apply B frags)
#define INV1  (1.f / (float)(N0c * NAt * NAt))
#define INV2  (1.f / (float)(N0c * NAt))
#define NBLK2 768   // k_conv grid: 2 rows/block, guaranteed >=3 blocks/CU

typedef __attribute__((ext_vector_type(8))) short short8_t;   // 8 bf16
typedef __attribute__((ext_vector_type(4))) float f32x4;

__device__ __forceinline__ float sp_(float x){
    return fmaxf(x, 0.f) + __logf(1.f + __expf(-fabsf(x)));
}
__device__ __forceinline__ float sgm_(float x){
    return 1.f / (1.f + __expf(-x));
}
__device__ __forceinline__ unsigned short bfhi(float x){
    union { float f; unsigned u; } v; v.f = x;
    unsigned r = v.u + 0x7fff + ((v.u >> 16) & 1);   // RNE to bf16
    return (unsigned short)(r >> 16);
}
__device__ __forceinline__ float bf2f(unsigned short h){
    union { float f; unsigned u; } v; v.u = ((unsigned)h) << 16; return v.f;
}

// Device-wide barrier (R2-verified correct): release fence + arrive,
// tid0 spins, block acquire fence. Counters zeroed by k_prep.
__device__ __forceinline__ void gbar(unsigned* __restrict__ bar, int slot){
    __syncthreads();
    if (threadIdx.x == 0){
        __threadfence();
        atomicAdd(&bar[slot], 1u);
        while (atomicAdd(&bar[slot], 0u) < (unsigned)NBLK2)
            __builtin_amdgcn_s_sleep(2);
    }
    __syncthreads();
    __threadfence();
}

// Compact-ws fallback only: S_r, T_r, cnt_r.
__global__ __launch_bounds__(256) void k_pre(const float* __restrict__ nbr,
                                             const int*   __restrict__ adj,
                                             float* __restrict__ ST,
                                             float* __restrict__ cntf){
    int r    = blockIdx.x;
    int lane = threadIdx.x & 63;
    int jg   = __builtin_amdgcn_readfirstlane(threadIdx.x >> 6);
    __shared__ float rS[JG][Kc], rT[JG][Kc], rc[JG];
    float S = 0.f, T = 0.f, cn = 0.f;
    int j0 = jg * JPW;
    for (int j = j0; j < j0 + JPW; ++j){
        float a = (float)adj[r * NAt + j];
        float v = (lane < Kc) ? nbr[((size_t)r * NAt + j) * Kc + lane] : 0.f;
        S += v; T += a * v; cn += a;
    }
    if (lane < Kc){ rS[jg][lane] = S; rT[jg][lane] = T; }
    if (lane == 0) rc[jg] = cn;
    __syncthreads();
    int t = threadIdx.x;
    if (t < Kc){
        ST[r * (2 * Kc) + t]      = rS[0][t] + rS[1][t] + rS[2][t] + rS[3][t];
        ST[r * (2 * Kc) + Kc + t] = rT[0][t] + rT[1][t] + rT[2][t] + rT[3][t];
    }
    if (t == 0) cntf[r] = rc[0] + rc[1] + rc[2] + rc[3];
}

// Gram partials + (fused) S/T/cnt + G-zeroing (verified).
__global__ __launch_bounds__(128) void k_gram(const float* __restrict__ nbr,
                                              const int*   __restrict__ adj,
                                              float* __restrict__ pG,
                                              float* __restrict__ ST,
                                              float* __restrict__ cntf,
                                              float* __restrict__ G,
                                              int rpb, int doST){
    int blk = blockIdx.x;
    int t   = threadIdx.x;
    int k   = (t % 21) * 2;
    int lb  = (t / 21) * 7;
    __shared__ float L[NAt * Kc];
    __shared__ float AJf[NAt];
    if (blk == 0){
        for (int i = t; i < Kc * Kc; i += 128) G[i] = 0.f;
    }
    float a0[7] = {0,0,0,0,0,0,0}, a1[7] = {0,0,0,0,0,0,0};
    for (int rr = 0; rr < rpb; ++rr){
        int r = blk * rpb + rr;
        __syncthreads();
        for (int i = t; i < NAt * Kc; i += 128)
            L[i] = nbr[(size_t)r * NAt * Kc + i];
        if (t < NAt) AJf[t] = (float)adj[r * NAt + t];
        __syncthreads();
        if (doST && t < Kc){
            float S = 0.f, T = 0.f;
            for (int j = 0; j < NAt; ++j){
                float v = L[j * Kc + t];
                S += v; T += AJf[j] * v;
            }
            ST[r * (2 * Kc) + t]      = S;
            ST[r * (2 * Kc) + Kc + t] = T;
        }
        if (doST && t == Kc){
            float cn = 0.f;
            for (int j = 0; j < NAt; ++j) cn += AJf[j];
            cntf[r] = cn;
        }
        if (t < 126){
            for (int j = 0; j < NAt; ++j){
                float vk0 = L[j * Kc + k];
                float vk1 = (k + 1 < Kc) ? L[j * Kc + k + 1] : 0.f;
                #pragma unroll
                for (int m = 0; m < 7; ++m){
                    if (lb + m < Kc){
                        float lv = L[j * Kc + lb + m];
                        a0[m] += vk0 * lv;
                        a1[m] += vk1 * lv;
                    }
                }
            }
        }
    }
    if (t < 126){
        float* dst = pG + (size_t)blk * (Kc * Kc);
        #pragma unroll
        for (int m = 0; m < 7; ++m){
            if (lb + m < Kc){
                dst[k * Kc + lb + m] = a0[m];
                if (k + 1 < Kc) dst[(k + 1) * Kc + lb + m] = a1[m];
            }
        }
    }
}

__global__ __launch_bounds__(64) void k_gred(const float* __restrict__ pG,
                                             float* __restrict__ G){
    int i  = (blockIdx.x % 27) * 64 + threadIdx.x;
    int b0 = (blockIdx.x / 27) * 96;
    if (i < Kc * Kc){
        float s = 0.f;
        #pragma unroll 4
        for (int b = b0; b < b0 + 96; ++b) s += pG[(size_t)b * (Kc * Kc) + i];
        atomicAdd(&G[i], s);
    }
}

// One-time prep, WIDE (verified) + R17: also zeroes SRL replicas and the
// coop barrier counters (replaces the hipMemsetAsync dispatch; pG is dead
// by the time k_prep runs in every workspace tier).
__global__ __launch_bounds__(320) void k_prep(const float* __restrict__ G,
                                              const float* __restrict__ convW,
                                              float* __restrict__ W3T,
                                              unsigned short* __restrict__ W3F,
                                              float* __restrict__ q3,
                                              float* __restrict__ SRL,
                                              unsigned* __restrict__ bar){
    int bi   = blockIdx.x;
    int l    = bi >> 5;
    int g    = bi & 31;
    int tid  = threadIdx.x;
    int lane = tid & 63;
    int w    = __builtin_amdgcn_readfirstlane(tid >> 6);   // 0..4
    const float* Wl = convW + (size_t)l * 169 * C2;
    __shared__ float GL[Kc * Kc];
    __shared__ float w3s[4][Kc];
    for (int i = tid; i < Kc * Kc; i += 320) GL[i] = G[i];

    // fold-in: zero stats replicas + barrier counters
    for (int i = bi * 320 + tid; i < 3 * SRL_STRIDE; i += 96 * 320) SRL[i] = 0.f;
    if (bi == 0 && tid < 64) bar[tid] = 0u;

    int   c  = g * 4 + (w & 3);
    float w3 = 0.f;
    if (w < 4){
        w3 = (lane < Kc) ? Wl[(C2 + lane) * C2 + c] : 0.f;
        if (lane < 44)
            W3T[((size_t)l * C2 + c) * 44 + lane] = (lane < Kc) ? w3 : 0.f;
        if (lane < Kc) w3s[w][lane] = w3;
    }
    __syncthreads();

    if (w == 4){
        int h  = g & 1;
        int ks = (g >> 1) & 1;
        int nt = g >> 2;
        int n  = nt * 16 + (lane & 15);
        unsigned short* dst = W3F + (size_t)l * WFRAG + g * 512 + lane * 8;
        #pragma unroll
        for (int i = 0; i < 8; ++i){
            int kk = ks * 32 + (lane >> 4) * 8 + i;
            float x = (kk < Kc) ? Wl[(C2 + kk) * C2 + n] : 0.f;
            unsigned short hi = bfhi(x);
            dst[i] = h ? bfhi(x - bf2f(hi)) : hi;
        }
    } else {
        float gw = 0.f;
        if (lane < Kc){
            #pragma unroll
            for (int m = 0; m < Kc; ++m) gw += GL[lane * Kc + m] * w3s[w][m];
        }
        float part = (lane < Kc) ? w3 * gw : 0.f;
        part += __shfl_xor(part, 1);
        part += __shfl_xor(part, 2);
        part += __shfl_xor(part, 4);
        part += __shfl_xor(part, 8);
        part += __shfl_xor(part, 16);
        part += __shfl_xor(part, 32);
        if (lane == 0) q3[l * C2 + c] = part;
    }
}

// R17 fused conv stack + final. 768 blocks x 256 threads, 2 rows/block.
// __launch_bounds__(256,3) guarantees >=3 blocks/CU co-residency (LDS 36KB
// -> 4/CU; threads -> 8/CU), so grid 768 is deadlock-proof for gbar.
// Front/apply/final bodies are ports of the verified dispatch kernels;
// apply runs 4 waves with an mh loop (identical MFMA math). p1/p2 LDS-only.
__global__ __launch_bounds__(256, 3)
void k_conv(const float* __restrict__ nbr,
            const int*   __restrict__ adj,
            const float* __restrict__ atom,
            const float* __restrict__ embW,
            const float* __restrict__ embB,
            const float* __restrict__ convW,
            const float* __restrict__ convB,
            const float* __restrict__ W3T,
            const unsigned short* __restrict__ W3F,
            const float* __restrict__ q3,
            const float* __restrict__ ST,
            const float* __restrict__ cntf,
            const float* __restrict__ bn1g,
            const float* __restrict__ bn1b,
            const float* __restrict__ bn2g,
            const float* __restrict__ bn2b,
            const float* __restrict__ fcW,
            const float* __restrict__ fcb,
            const float* __restrict__ outW,
            const float* __restrict__ outb,
            float* __restrict__ fea,
            float* __restrict__ summed,
            float* __restrict__ SRL,
            unsigned* __restrict__ bar,
            float* __restrict__ out){
    int b    = blockIdx.x;
    int tid  = threadIdx.x;
    int lane = tid & 63;
    int w4   = __builtin_amdgcn_readfirstlane(tid >> 6);   // 0..3 (= ntF)
    int half = __builtin_amdgcn_readfirstlane(tid >> 7);   // 0/1 front halves
    int c    = tid & 127;
    int slot = b & (NREP - 1);

    __shared__ unsigned short sAH[NAt * AROW];
    __shared__ unsigned short sAL[NAt * AROW];
    __shared__ float FE[2][Fc], SM[2][Fc];
    __shared__ float P1[2][C2], P2[2][C2];
    __shared__ float A1L[C2], B1L[C2], A2L[Fc], B2L[Fc];
    __shared__ float AJ[NAt];
    __shared__ float TpW[8][16];
    __shared__ float P1h[C2], P2h[C2], TTs[C2];
    __shared__ float prt[4][Fc];
    __shared__ float spc[Fc], red[Hc];

    // one-time zero of MFMA pad cols 41..71 (31 cols per row)
    for (int idx = tid; idx < NAt * 31; idx += 256){
        int j = idx / 31, k = Kc + (idx - j * 31);
        sAH[j * AROW + k] = 0;
        sAL[j * AROW + k] = 0;
    }

    for (int l = 0; l < NCc; ++l){
        const float* Wl   = convW + (size_t)l * 169 * C2;
        const float* blp  = convB + l * C2;
        const float* W3Tl = W3T + (size_t)l * C2 * 44;
        float* sum1R = SRL + l * SRL_STRIDE;
        float* sq1R  = sum1R + 4096;
        float* sum2R = sum1R + 8192;
        float* sq2R  = sum1R + 10240;

        // ---- front(l) ----
        if (l > 0){
            const float* sum2Rp = SRL + (l - 1) * SRL_STRIDE + 8192;
            const float* sq2Rp  = sum2Rp + 2048;
            const float* g2p    = bn2g + (l - 1) * Fc;
            const float* b2p    = bn2b + (l - 1) * Fc;
            if (tid < Fc){
                float s = 0.f, q = 0.f;
                for (int rr = 0; rr < NREP; ++rr){
                    s += sum2Rp[rr * Fc + tid];
                    q += sq2Rp[rr * Fc + tid];
                }
                float m = s * INV2;
                float v = q * INV2 - m * m;
                float A = g2p[tid] * rsqrtf(v + EPSBN);
                A2L[tid] = A;
                B2L[tid] = b2p[tid] - m * A;
            }
        }
        __syncthreads();

        for (int ri = 0; ri < 2; ++ri){
            int r = 2 * b + ri;
            if (tid < Fc){
                float nv;
                if (l > 0){
                    nv = sp_(FE[ri][tid] + SM[ri][tid] * A2L[tid] + B2L[tid]);
                } else {
                    const float* ar = atom + r * ORIG;
                    float acc = embB[tid];
                    #pragma unroll 4
                    for (int o = 0; o < ORIG; ++o) acc += ar[o] * embW[o * Fc + tid];
                    nv = acc;
                }
                FE[ri][tid] = nv;
                if (l == NCc - 1) fea[r * Fc + tid] = nv;   // for final phase
            }
            __syncthreads();

            float a1p = 0.f, a2p = 0.f;
            int f0 = half * 32;
            #pragma unroll 8
            for (int f = f0; f < f0 + 32; ++f){
                float fv = FE[ri][f];
                a1p += fv * Wl[f * C2 + c];
                a2p += fv * Wl[(Fc + f) * C2 + c];
            }
            const float* wt = W3Tl + c * 44;
            const float* Sr = ST + r * (2 * Kc) + half * Kc;
            float dot = 0.f;
            #pragma unroll
            for (int k = 0; k < 40; k += 4){
                float4 wv = *(const float4*)(wt + k);
                dot += Sr[k] * wv.x + Sr[k + 1] * wv.y + Sr[k + 2] * wv.z + Sr[k + 3] * wv.w;
            }
            dot += Sr[40] * wt[40];

            if (half == 1){ P1h[c] = a1p; P2h[c] = a2p; TTs[c] = dot; }
            __syncthreads();
            if (half == 0){
                float a1  = a1p + P1h[c] + blp[c];
                float a2  = a2p + P2h[c];
                float u   = dot;
                float ttv = TTs[c];
                P1[ri][c] = a1;
                P2[ri][c] = a2;
                float cn = cntf[r];
                float s1 = (float)NAt * a1 + cn * a2 + u;
                float q1 = (float)NAt * a1 * a1 + cn * a2 * a2
                         + 2.f * cn * a1 * a2 + 2.f * a1 * u + 2.f * a2 * ttv;
                atomicAdd(&sum1R[slot * C2 + c], s1);
                atomicAdd(&sq1R[slot * C2 + c], q1);
            }
            __syncthreads();
        }
        gbar(bar, 2 * l);            // bn1 stats complete

        // ---- apply(l) ----
        if (tid < C2){
            float s = 0.f, qq = 0.f;
            for (int rr = 0; rr < NREP; ++rr){
                s += sum1R[rr * C2 + tid]; qq += sq1R[rr * C2 + tid];
            }
            float m = s * INV1;
            float v = (qq + q3[l * C2 + tid]) * INV1 - m * m;
            float A = bn1g[l * C2 + tid] * rsqrtf(v + EPSBN);
            A1L[tid] = A;
            B1L[tid] = bn1b[l * C2 + tid] - m * A;
        }
        const unsigned short* W3Fl = W3F + (size_t)l * WFRAG;
        short8_t BH[2][2], BL[2][2];
        #pragma unroll
        for (int ni = 0; ni < 2; ++ni){
            int nt = w4 + ni * 4;
            #pragma unroll
            for (int ks = 0; ks < 2; ++ks){
                int fidH = (nt * 2 + ks) * 2;
                BH[ni][ks] = *(const short8_t*)(W3Fl + fidH * 512 + lane * 8);
                BL[ni][ks] = *(const short8_t*)(W3Fl + (fidH + 1) * 512 + lane * 8);
            }
        }

        for (int ri = 0; ri < 2; ++ri){
            int r = 2 * b + ri;
            const float* nb = nbr + (size_t)r * (NAt * Kc);
            {   // stage row -> bf16 hi/lo LDS (incremental div by 41)
                int idx = tid;
                int jj  = tid / Kc;
                int kk  = tid - jj * Kc;
                while (idx < NAt * Kc){
                    float x = nb[idx];
                    unsigned short hi = bfhi(x);
                    sAH[jj * AROW + kk] = hi;
                    sAL[jj * AROW + kk] = bfhi(x - bf2f(hi));
                    idx += 256; jj += 6; kk += 10;
                    if (kk >= Kc){ kk -= Kc; ++jj; }
                }
            }
            if (tid < NAt) AJ[tid] = (float)adj[r * NAt + tid];
            __syncthreads();

            int q4 = (lane >> 4) * 8;
            int cF = w4 * 16 + (lane & 15);
            int cC = cF + 64;
            float p1F = P1[ri][cF], p2F = P1 == P2 ? 0.f : P2[ri][cF];
            float A1F = A1L[cF], B1F = B1L[cF];
            float p1C = P1[ri][cC], p2C = P2[ri][cC];
            float A1C = A1L[cC], B1C = B1L[cC];
            #pragma unroll
            for (int mh = 0; mh < 2; ++mh){
                f32x4 acc[3][2] = {};
                #pragma unroll
                for (int mt = 0; mt < 3; ++mt){
                    int jrow = (mh * 48 + mt * 16 + (lane & 15)) * AROW;
                    short8_t AH0 = *(const short8_t*)(&sAH[jrow + q4]);
                    short8_t AH1 = *(const short8_t*)(&sAH[jrow + 32 + q4]);
                    short8_t AL0 = *(const short8_t*)(&sAL[jrow + q4]);
                    short8_t AL1 = *(const short8_t*)(&sAL[jrow + 32 + q4]);
                    #pragma unroll
                    for (int ni = 0; ni < 2; ++ni){
                        acc[mt][ni] = __builtin_amdgcn_mfma_f32_16x16x32_bf16(AH0, BH[ni][0], acc[mt][ni], 0, 0, 0);
                        acc[mt][ni] = __builtin_amdgcn_mfma_f32_16x16x32_bf16(AH0, BL[ni][0], acc[mt][ni], 0, 0, 0);
                        acc[mt][ni] = __builtin_amdgcn_mfma_f32_16x16x32_bf16(AL0, BH[ni][0], acc[mt][ni], 0, 0, 0);
                        acc[mt][ni] = __builtin_amdgcn_mfma_f32_16x16x32_bf16(AH1, BH[ni][1], acc[mt][ni], 0, 0, 0);
                        acc[mt][ni] = __builtin_amdgcn_mfma_f32_16x16x32_bf16(AH1, BL[ni][1], acc[mt][ni], 0, 0, 0);
                        acc[mt][ni] = __builtin_amdgcn_mfma_f32_16x16x32_bf16(AL1, BH[ni][1], acc[mt][ni], 0, 0, 0);
                    }
                }
                float tsum = 0.f;
                #pragma unroll
                for (int mt = 0; mt < 3; ++mt){
                    #pragma unroll
                    for (int rg = 0; rg < 4; ++rg){
                        int j = mh * 48 + mt * 16 + (lane >> 4) * 4 + rg;
                        float ajf = AJ[j];
                        float gf = (p1F + ajf * p2F + acc[mt][0][rg]) * A1F + B1F;
                        float gc = (p1C + ajf * p2C + acc[mt][1][rg]) * A1C + B1C;
                        tsum += sgm_(gf) * sp_(gc);
                    }
                }
                tsum += __shfl_xor(tsum, 16);
                tsum += __shfl_xor(tsum, 32);
                if (lane < 16) TpW[(mh << 2) | w4][lane] = tsum;
            }
            __syncthreads();
            if (tid < Fc){
                float s = TpW[tid >> 4][tid & 15] + TpW[(tid >> 4) + 4][tid & 15];
                SM[ri][tid] = s;
                if (l == NCc - 1) summed[r * Fc + tid] = s;   // for final phase
                atomicAdd(&sum2R[slot * Fc + tid], s);
                atomicAdd(&sq2R[slot * Fc + tid], s * s);
            }
            __syncthreads();
        }
        gbar(bar, 2 * l + 1);        // bn2 stats complete
    }

    // ---- final (blocks 0..15) ----
    if (b < N0c){
        const float* s2 = SRL + 2 * SRL_STRIDE + 8192;
        const float* q2 = s2 + 2048;
        const float* g2 = bn2g + 2 * Fc;
        const float* b2 = bn2b + 2 * Fc;
        if (tid < Fc){
            float s = 0.f, q = 0.f;
            for (int rr = 0; rr < NREP; ++rr){
                s += s2[rr * Fc + tid]; q += q2[rr * Fc + tid];
            }
            float m  = s * INV2;
            float v  = q * INV2 - m * m;
            float A2 = g2[tid] * rsqrtf(v + EPSBN);
            A2L[tid] = A2;
            B2L[tid] = b2[tid] - m * A2;
        }
        __syncthreads();
        int tg = tid >> 6, t2 = tid & 63;
        float accp = 0.f;
        for (int i = tg * 24; i < tg * 24 + 24; ++i){
            int idx = (b * NAt + i) * Fc + t2;
            accp += sp_(fea[idx] + summed[idx] * A2L[t2] + B2L[t2]);
        }
        prt[tg][t2] = accp;
        __syncthreads();
        if (tid < Fc)
            spc[tid] = sp_((prt[0][tid] + prt[1][tid] + prt[2][tid] + prt[3][tid]) * (1.f / NAt));
        __syncthreads();
        if (tid < Hc){
            float h = fcb[tid];
            #pragma unroll 4
            for (int f = 0; f < Fc; ++f) h += spc[f] * fcW[f * Hc + tid];
            red[tid] = sp_(h) * outW[tid];
        }
        __syncthreads();
        for (int off = 64; off > 0; off >>= 1){
            if (tid < off) red[tid] += red[tid + off];
            __syncthreads();
        }
        if (tid == 0) out[b] = red[0] + outb[0];
    }
}

extern "C" void kernel_launch(void* const* d_in, const int* in_sizes, int n_in,
                              void* d_out, int out_size, void* d_ws, size_t ws_size,
                              hipStream_t stream){
    const float* atom  = (const float*)d_in[0];
    const float* nbr   = (const float*)d_in[1];
    const int*   adj   = (const int*)  d_in[2];
    const float* embW  = (const float*)d_in[3];
    const float* embB  = (const float*)d_in[4];
    const float* convW = (const float*)d_in[5];
    const float* convB = (const float*)d_in[6];
    const float* bn1g  = (const float*)d_in[7];
    const float* bn1b  = (const float*)d_in[8];
    const float* bn2g  = (const float*)d_in[9];
    const float* bn2b  = (const float*)d_in[10];
    const float* fcW   = (const float*)d_in[11];
    const float* fcb   = (const float*)d_in[12];
    const float* outW  = (const float*)d_in[13];
    const float* outb  = (const float*)d_in[14];
    float* out = (float*)d_out;
    float* ws  = (float*)d_ws;

    const int ROWS = N0c * NAt;            // 1536
    float* fea    = ws;                    // 98304 (layer-2 rows, final phase)
    unsigned* bar = (unsigned*)(ws + 98304);  // barrier counters (old p1, free)
    float* summed = ws + 491520;           // 98304 (layer-2 only)
    float* SRL    = ws + 589824;           // 3 * 12288
    float* ST     = ws + 626688;           // 125952
    float* cntf   = ws + 752640;           // 1536
    float* q3     = ws + 754176;           // 384
    float* W3T    = ws + 754560;           // 16896
    unsigned short* W3F = (unsigned short*)(ws + 771456);  // 24576 f
    const size_t PERS = 796032;

    size_t ws_f = ws_size / sizeof(float);
    int nblk; float *pG, *G; int compact = 0;
    if (ws_f >= PERS + (size_t)1536 * 1681 + 1681 + 64){
        nblk = 1536; pG = ws + PERS; G = pG + (size_t)nblk * 1681;
    } else if (ws_f >= PERS + (size_t)768 * 1681 + 1681 + 64){
        nblk = 768;  pG = ws + PERS; G = pG + (size_t)nblk * 1681;
    } else if (ws_f >= PERS + (size_t)384 * 1681 + 1681 + 64){
        nblk = 384;  pG = ws + PERS; G = pG + (size_t)nblk * 1681;
    } else {
        // compact overlay: pG over ws head (dead after gred); G inside ST
        // region — ST then comes from the separate k_pre AFTER k_prep ran.
        nblk = 384;  pG = ws;        G = ws + 650000;  compact = 1;
    }
    int rpb = 1536 / nblk;
    int ph  = nblk / 96;

    // 1: gram (+ST/cnt fused unless compact; zeroes G from block 0)
    k_gram <<<nblk, 128, 0, stream>>>(nbr, adj, pG, ST, cntf, G, rpb,
                                      compact ? 0 : 1);
    // 2: reduce gram partials into G
    k_gred <<<27 * ph, 64, 0, stream>>>(pG, G);
    // 3: weight prep + SRL/bar zeroing (pG dead; replaces memset dispatch)
    k_prep <<<NCc * 32, 320, 0, stream>>>(G, convW, W3T, W3F, q3, SRL, bar);
    // 3b (compact tier only): ST/cnt via standalone pre (after G consumed)
    if (compact)
        k_pre <<<ROWS, 256, 0, stream>>>(nbr, adj, ST, cntf);
    // 4: fused conv stack + final (co-resident persistent grid)
    k_conv <<<NBLK2, 256, 0, stream>>>(nbr, adj, atom, embW, embB, convW, convB,
                                       W3T, W3F, q3, ST, cntf,
                                       bn1g, bn1b, bn2g, bn2b,
                                       fcW, fcb, outW, outb,
                                       fea, summed, SRL, bar, out);
}

// Round 6
// 258.125 us; speedup vs baseline: 3.7570x; 3.7570x over previous
//
#include <hip/hip_runtime.h>
#include <math.h>

#define N0c   16
#define NAt   96
#define ORIG  92
#define Fc    64
#define Kc    41
#define Hc    128
#define NCc   3
#define C2    128   // 2F
#define EPSBN 1e-5f
#define JG    4
#define JPW   (NAt / JG)
#define NREP  32    // atomic replica slots
#define SRL_STRIDE 12288   // per-layer replica block
#define AROW  72    // k_apply LDS A row stride (ushorts)
#define WFRAG 16384 // ushorts per layer in W3F (k_apply B frags)
#define INV1  (1.f / (float)(N0c * NAt * NAt))
#define INV2  (1.f / (float)(N0c * NAt))

typedef __attribute__((ext_vector_type(8))) short short8_t;   // 8 bf16
typedef __attribute__((ext_vector_type(4))) float f32x4;

__device__ __forceinline__ float sp_(float x){
    return fmaxf(x, 0.f) + __logf(1.f + __expf(-fabsf(x)));
}
__device__ __forceinline__ float sgm_(float x){
    return 1.f / (1.f + __expf(-x));
}
__device__ __forceinline__ unsigned short bfhi(float x){
    union { float f; unsigned u; } v; v.f = x;
    unsigned r = v.u + 0x7fff + ((v.u >> 16) & 1);   // RNE to bf16
    return (unsigned short)(r >> 16);
}
__device__ __forceinline__ float bf2f(unsigned short h){
    union { float f; unsigned u; } v; v.u = ((unsigned)h) << 16; return v.f;
}

// Compact-ws fallback only: S_r, T_r, cnt_r (identical to R15 k_pre).
__global__ __launch_bounds__(256) void k_pre(const float* __restrict__ nbr,
                                             const int*   __restrict__ adj,
                                             float* __restrict__ ST,
                                             float* __restrict__ cntf){
    int r    = blockIdx.x;
    int lane = threadIdx.x & 63;
    int jg   = __builtin_amdgcn_readfirstlane(threadIdx.x >> 6);
    __shared__ float rS[JG][Kc], rT[JG][Kc], rc[JG];
    float S = 0.f, T = 0.f, cn = 0.f;
    int j0 = jg * JPW;
    for (int j = j0; j < j0 + JPW; ++j){
        float a = (float)adj[r * NAt + j];
        float v = (lane < Kc) ? nbr[((size_t)r * NAt + j) * Kc + lane] : 0.f;
        S += v; T += a * v; cn += a;
    }
    if (lane < Kc){ rS[jg][lane] = S; rT[jg][lane] = T; }
    if (lane == 0) rc[jg] = cn;
    __syncthreads();
    int t = threadIdx.x;
    if (t < Kc){
        ST[r * (2 * Kc) + t]      = rS[0][t] + rS[1][t] + rS[2][t] + rS[3][t];
        ST[r * (2 * Kc) + Kc + t] = rT[0][t] + rT[1][t] + rT[2][t] + rT[3][t];
    }
    if (t == 0) cntf[r] = rc[0] + rc[1] + rc[2] + rc[3];
}

// Gram partials + (fused) S/T/cnt + G-zeroing (verified R13/R16 inner loop).
__global__ __launch_bounds__(128) void k_gram(const float* __restrict__ nbr,
                                              const int*   __restrict__ adj,
                                              float* __restrict__ pG,
                                              float* __restrict__ ST,
                                              float* __restrict__ cntf,
                                              float* __restrict__ G,
                                              int rpb, int doST){
    int blk = blockIdx.x;
    int t   = threadIdx.x;
    int k   = (t % 21) * 2;
    int lb  = (t / 21) * 7;
    __shared__ float L[NAt * Kc];
    __shared__ float AJf[NAt];
    if (blk == 0){                                   // zero G (consumed by gred)
        for (int i = t; i < Kc * Kc; i += 128) G[i] = 0.f;
    }
    float a0[7] = {0,0,0,0,0,0,0}, a1[7] = {0,0,0,0,0,0,0};
    for (int rr = 0; rr < rpb; ++rr){
        int r = blk * rpb + rr;
        __syncthreads();
        for (int i = t; i < NAt * Kc; i += 128)
            L[i] = nbr[(size_t)r * NAt * Kc + i];
        if (t < NAt) AJf[t] = (float)adj[r * NAt + t];
        __syncthreads();
        if (doST && t < Kc){                         // S/T from LDS tile
            float S = 0.f, T = 0.f;
            for (int j = 0; j < NAt; ++j){
                float v = L[j * Kc + t];
                S += v; T += AJf[j] * v;
            }
            ST[r * (2 * Kc) + t]      = S;
            ST[r * (2 * Kc) + Kc + t] = T;
        }
        if (doST && t == Kc){
            float cn = 0.f;
            for (int j = 0; j < NAt; ++j) cn += AJf[j];
            cntf[r] = cn;
        }
        if (t < 126){
            for (int j = 0; j < NAt; ++j){
                float vk0 = L[j * Kc + k];
                float vk1 = (k + 1 < Kc) ? L[j * Kc + k + 1] : 0.f;
                #pragma unroll
                for (int m = 0; m < 7; ++m){
                    if (lb + m < Kc){
                        float lv = L[j * Kc + lb + m];
                        a0[m] += vk0 * lv;
                        a1[m] += vk1 * lv;
                    }
                }
            }
        }
    }
    if (t < 126){
        float* dst = pG + (size_t)blk * (Kc * Kc);
        #pragma unroll
        for (int m = 0; m < 7; ++m){
            if (lb + m < Kc){
                dst[k * Kc + lb + m] = a0[m];
                if (k + 1 < Kc) dst[(k + 1) * Kc + lb + m] = a1[m];
            }
        }
    }
}

__global__ __launch_bounds__(64) void k_gred(const float* __restrict__ pG,
                                             float* __restrict__ G){
    int i  = (blockIdx.x % 27) * 64 + threadIdx.x;
    int b0 = (blockIdx.x / 27) * 96;
    if (i < Kc * Kc){
        float s = 0.f;
        #pragma unroll 4
        for (int b = b0; b < b0 + 96; ++b) s += pG[(size_t)b * (Kc * Kc) + i];
        atomicAdd(&G[i], s);
    }
}

// One-time prep, WIDE (R16-verified) + R6: grid-stride zero of the SRL
// replica region (replaces the hipMemsetAsync dispatch; pG overlap is dead
// by k_prep time in every workspace tier).
__global__ __launch_bounds__(320) void k_prep(const float* __restrict__ G,
                                              const float* __restrict__ convW,
                                              float* __restrict__ W3T,
                                              unsigned short* __restrict__ W3F,
                                              float* __restrict__ q3,
                                              float* __restrict__ SRL){
    int bi   = blockIdx.x;
    int l    = bi >> 5;            // /32  -> layer
    int g    = bi & 31;            // group within layer
    int tid  = threadIdx.x;
    int lane = tid & 63;
    int w    = __builtin_amdgcn_readfirstlane(tid >> 6);   // 0..4
    const float* Wl = convW + (size_t)l * 169 * C2;
    __shared__ float GL[Kc * Kc];
    __shared__ float w3s[4][Kc];
    for (int i = tid; i < Kc * Kc; i += 320) GL[i] = G[i];

    // fold-in: zero stats replicas (was a separate hipMemsetAsync dispatch)
    for (int i = bi * 320 + tid; i < 3 * SRL_STRIDE; i += 96 * 320) SRL[i] = 0.f;

    int   c  = g * 4 + (w & 3);
    float w3 = 0.f;
    if (w < 4){
        w3 = (lane < Kc) ? Wl[(C2 + lane) * C2 + c] : 0.f;
        if (lane < 44)
            W3T[((size_t)l * C2 + c) * 44 + lane] = (lane < Kc) ? w3 : 0.f;
        if (lane < Kc) w3s[w][lane] = w3;
    }
    __syncthreads();

    if (w == 4){
        // W3F fragments: fid = g, 64 lanes of this wave
        int h  = g & 1;
        int ks = (g >> 1) & 1;
        int nt = g >> 2;
        int n  = nt * 16 + (lane & 15);
        unsigned short* dst = W3F + (size_t)l * WFRAG + g * 512 + lane * 8;
        #pragma unroll
        for (int i = 0; i < 8; ++i){
            int kk = ks * 32 + (lane >> 4) * 8 + i;
            float x = (kk < Kc) ? Wl[(C2 + kk) * C2 + n] : 0.f;
            unsigned short hi = bfhi(x);
            dst[i] = h ? bfhi(x - bf2f(hi)) : hi;
        }
    } else {
        float gw = 0.f;
        if (lane < Kc){
            #pragma unroll
            for (int m = 0; m < Kc; ++m) gw += GL[lane * Kc + m] * w3s[w][m];
        }
        float part = (lane < Kc) ? w3 * gw : 0.f;
        part += __shfl_xor(part, 1);
        part += __shfl_xor(part, 2);
        part += __shfl_xor(part, 4);
        part += __shfl_xor(part, 8);
        part += __shfl_xor(part, 16);
        part += __shfl_xor(part, 32);
        if (lane == 0) q3[l * C2 + c] = part;
    }
}

// Front (R15 v3 structure + embed fold; measured-best R1 variant).
__global__ __launch_bounds__(256)
void k_front(float* __restrict__ fea,
             const float* __restrict__ atom,
             const float* __restrict__ embW,
             const float* __restrict__ embB,
             const float* __restrict__ Wl,
             const float* __restrict__ bl,
             const float* __restrict__ W3Tl,
             const float* __restrict__ ST,
             const float* __restrict__ cntf,
             float* __restrict__ p1,
             float* __restrict__ p2,
             float* __restrict__ sum1R,
             float* __restrict__ sq1R,
             const float* __restrict__ summed,
             const float* __restrict__ sum2Rp,
             const float* __restrict__ sq2Rp,
             const float* __restrict__ g2p,
             const float* __restrict__ b2p,
             int upd){
    int r    = blockIdx.x;
    int tid  = threadIdx.x;
    int c    = tid & 127;
    int half = __builtin_amdgcn_readfirstlane(tid >> 7);
    __shared__ float F[Fc];
    __shared__ float A2L[Fc], B2L[Fc];
    __shared__ float P1h[C2], P2h[C2], TTs[C2];

    if (upd){
        if (tid < Fc){
            float s = 0.f, q = 0.f;
            for (int rr = 0; rr < NREP; ++rr){
                s += sum2Rp[rr * Fc + tid];
                q += sq2Rp[rr * Fc + tid];
            }
            float m = s * INV2;
            float v = q * INV2 - m * m;
            float A = g2p[tid] * rsqrtf(v + EPSBN);
            A2L[tid] = A;
            B2L[tid] = b2p[tid] - m * A;
        }
        __syncthreads();
        if (tid < Fc){
            float nv = sp_(fea[r * Fc + tid] + summed[r * Fc + tid] * A2L[tid] + B2L[tid]);
            F[tid] = nv;
            fea[r * Fc + tid] = nv;          // persist for next front / k_final
        }
        __syncthreads();
    } else {
        // l==0: embed inline (atom row is wave-uniform -> s_loads)
        if (tid < Fc){
            const float* ar = atom + r * ORIG;
            float acc = embB[tid];
            #pragma unroll 4
            for (int o = 0; o < ORIG; ++o) acc += ar[o] * embW[o * Fc + tid];
            F[tid] = acc;
            fea[r * Fc + tid] = acc;         // consumed by front l=1
        }
        __syncthreads();
    }

    // p12 partial over f in [half*32, half*32+32)
    float a1p = 0.f, a2p = 0.f;
    int f0 = half * 32;
    #pragma unroll 8
    for (int f = f0; f < f0 + 32; ++f){
        float fv = F[f];                     // LDS broadcast
        a1p += fv * Wl[f * C2 + c];
        a2p += fv * Wl[(Fc + f) * C2 + c];
    }
    // dot: half 0 -> u = S·w3 ; half 1 -> tt = T·w3 (uniform s_loads of S/T)
    const float* wt = W3Tl + c * 44;
    const float* Sr = ST + r * (2 * Kc) + half * Kc;
    float dot = 0.f;
    #pragma unroll
    for (int k = 0; k < 40; k += 4){
        float4 wv = *(const float4*)(wt + k);
        dot += Sr[k] * wv.x + Sr[k + 1] * wv.y + Sr[k + 2] * wv.z + Sr[k + 3] * wv.w;
    }
    dot += Sr[40] * wt[40];

    if (half == 1){ P1h[c] = a1p; P2h[c] = a2p; TTs[c] = dot; }
    __syncthreads();
    if (half == 0){
        float a1 = a1p + P1h[c] + bl[c];
        float a2 = a2p + P2h[c];
        float u  = dot;
        float tt = TTs[c];
        p1[r * C2 + c] = a1;
        p2[r * C2 + c] = a2;
        float cn = cntf[r];
        float s1 = (float)NAt * a1 + cn * a2 + u;
        float q1 = (float)NAt * a1 * a1 + cn * a2 * a2
                 + 2.f * cn * a1 * a2 + 2.f * a1 * u + 2.f * a2 * tt;
        int slot = blockIdx.x & (NREP - 1);
        atomicAdd(&sum1R[slot * C2 + c], s1);
        atomicAdd(&sq1R[slot * C2 + c], q1);
    }
}

// Pass 2 (MFMA, identical to R13 — verified, ~35 us).
__global__ __launch_bounds__(512)
void k_apply(const float* __restrict__ nbr,
             const int*   __restrict__ adj,
             const unsigned short* __restrict__ W3Fl,
             const float* __restrict__ p1,
             const float* __restrict__ p2,
             const float* __restrict__ sum1R,
             const float* __restrict__ sq1R,
             const float* __restrict__ qv,
             const float* __restrict__ g1,
             const float* __restrict__ b1,
             float* __restrict__ summed,
             float* __restrict__ sum2R,
             float* __restrict__ sq2R){
    int r    = blockIdx.x;
    int tid  = threadIdx.x;
    int lane = tid & 63;
    int w    = __builtin_amdgcn_readfirstlane(tid >> 6);
    int ntF  = w & 3;
    int mh   = w >> 2;

    __shared__ unsigned short sAH[NAt * AROW];
    __shared__ unsigned short sAL[NAt * AROW];
    __shared__ float AJ[NAt];
    __shared__ float PL1[C2], PL2[C2], A1L[C2], B1L[C2];
    __shared__ float TpW[8][16];

    short8_t BH[2][2], BL[2][2];
    #pragma unroll
    for (int ni = 0; ni < 2; ++ni){
        int nt = ntF + ni * 4;
        #pragma unroll
        for (int ks = 0; ks < 2; ++ks){
            int fidH = (nt * 2 + ks) * 2;
            BH[ni][ks] = *(const short8_t*)(W3Fl + fidH * 512 + lane * 8);
            BL[ni][ks] = *(const short8_t*)(W3Fl + (fidH + 1) * 512 + lane * 8);
        }
    }

    const float* nb = nbr + (size_t)r * (NAt * Kc);
    for (int idx = tid; idx < NAt * Kc; idx += 512){
        int j = idx / Kc, k = idx - j * Kc;
        float x = nb[idx];
        unsigned short hi = bfhi(x);
        sAH[j * AROW + k] = hi;
        sAL[j * AROW + k] = bfhi(x - bf2f(hi));
    }
    for (int idx = tid; idx < NAt * 23; idx += 512){
        int j = idx / 23, k = Kc + (idx - j * 23);
        sAH[j * AROW + k] = 0;
        sAL[j * AROW + k] = 0;
    }
    if (tid < C2){
        int c = tid;
        float s = 0.f, q = 0.f;
        for (int rr = 0; rr < NREP; ++rr){ s += sum1R[rr * C2 + c]; q += sq1R[rr * C2 + c]; }
        float m = s * INV1;
        float v = (q + qv[c]) * INV1 - m * m;
        float A = g1[c] * rsqrtf(v + EPSBN);
        A1L[c] = A;
        B1L[c] = b1[c] - m * A;
    } else if (tid < 256){
        PL1[tid - 128] = p1[r * C2 + tid - 128];
    } else if (tid < 384){
        PL2[tid - 256] = p2[r * C2 + tid - 256];
    } else if (tid < 480){
        AJ[tid - 384] = (float)adj[r * NAt + tid - 384];
    }
    __syncthreads();

    f32x4 acc[3][2] = {};
    int q4 = (lane >> 4) * 8;
    #pragma unroll
    for (int mt = 0; mt < 3; ++mt){
        int jrow = (mh * 48 + mt * 16 + (lane & 15)) * AROW;
        short8_t AH0 = *(const short8_t*)(&sAH[jrow + q4]);
        short8_t AH1 = *(const short8_t*)(&sAH[jrow + 32 + q4]);
        short8_t AL0 = *(const short8_t*)(&sAL[jrow + q4]);
        short8_t AL1 = *(const short8_t*)(&sAL[jrow + 32 + q4]);
        #pragma unroll
        for (int ni = 0; ni < 2; ++ni){
            acc[mt][ni] = __builtin_amdgcn_mfma_f32_16x16x32_bf16(AH0, BH[ni][0], acc[mt][ni], 0, 0, 0);
            acc[mt][ni] = __builtin_amdgcn_mfma_f32_16x16x32_bf16(AH0, BL[ni][0], acc[mt][ni], 0, 0, 0);
            acc[mt][ni] = __builtin_amdgcn_mfma_f32_16x16x32_bf16(AL0, BH[ni][0], acc[mt][ni], 0, 0, 0);
            acc[mt][ni] = __builtin_amdgcn_mfma_f32_16x16x32_bf16(AH1, BH[ni][1], acc[mt][ni], 0, 0, 0);
            acc[mt][ni] = __builtin_amdgcn_mfma_f32_16x16x32_bf16(AH1, BL[ni][1], acc[mt][ni], 0, 0, 0);
            acc[mt][ni] = __builtin_amdgcn_mfma_f32_16x16x32_bf16(AL1, BH[ni][1], acc[mt][ni], 0, 0, 0);
        }
    }

    int cF = ntF * 16 + (lane & 15);
    int cC = cF + 64;
    float p1F = PL1[cF], p2F = PL2[cF], A1F = A1L[cF], B1F = B1L[cF];
    float p1C = PL1[cC], p2C = PL2[cC], A1C = A1L[cC], B1C = B1L[cC];
    float tsum = 0.f;
    #pragma unroll
    for (int mt = 0; mt < 3; ++mt){
        #pragma unroll
        for (int rg = 0; rg < 4; ++rg){
            int j = mh * 48 + mt * 16 + (lane >> 4) * 4 + rg;
            float ajf = AJ[j];
            float gf = (p1F + ajf * p2F + acc[mt][0][rg]) * A1F + B1F;
            float gc = (p1C + ajf * p2C + acc[mt][1][rg]) * A1C + B1C;
            tsum += sgm_(gf) * sp_(gc);
        }
    }
    tsum += __shfl_xor(tsum, 16);
    tsum += __shfl_xor(tsum, 32);
    if (lane < 16) TpW[w][lane] = tsum;
    __syncthreads();
    if (tid < Fc){
        int f = tid;
        float s = TpW[f >> 4][f & 15] + TpW[(f >> 4) + 4][f & 15];
        summed[r * Fc + f] = s;
        int slot = blockIdx.x & (NREP - 1);
        atomicAdd(&sum2R[slot * Fc + f], s);
        atomicAdd(&sq2R[slot * Fc + f], s * s);
    }
}

// Tail (identical to R13).
__global__ __launch_bounds__(128) void k_final(const float* __restrict__ fea,
                                               const float* __restrict__ summed,
                                               const float* __restrict__ sum2R,
                                               const float* __restrict__ sq2R,
                                               const float* __restrict__ g2,
                                               const float* __restrict__ b2,
                                               const float* __restrict__ fcW,
                                               const float* __restrict__ fcb,
                                               const float* __restrict__ outW,
                                               const float* __restrict__ outb,
                                               float* __restrict__ out){
    int b = blockIdx.x;
    int t = threadIdx.x;
    __shared__ float spc[Fc];
    __shared__ float red[Hc];
    if (t < Fc){
        float s = 0.f, q = 0.f;
        for (int r = 0; r < NREP; ++r){ s += sum2R[r * Fc + t]; q += sq2R[r * Fc + t]; }
        float m  = s * INV2;
        float v  = q * INV2 - m * m;
        float A2 = g2[t] * rsqrtf(v + EPSBN);
        float B2 = b2[t] - m * A2;
        float acc = 0.f;
        for (int i = 0; i < NAt; ++i){
            int idx = (b * NAt + i) * Fc + t;
            acc += sp_(fea[idx] + summed[idx] * A2 + B2);
        }
        spc[t] = sp_(acc * (1.f / NAt));
    }
    __syncthreads();
    float h = fcb[t];
    #pragma unroll 4
    for (int f = 0; f < Fc; ++f) h += spc[f] * fcW[f * Hc + t];
    h = sp_(h);
    red[t] = h * outW[t];
    __syncthreads();
    for (int off = 64; off > 0; off >>= 1){
        if (t < off) red[t] += red[t + off];
        __syncthreads();
    }
    if (t == 0) out[b] = red[0] + outb[0];
}

extern "C" void kernel_launch(void* const* d_in, const int* in_sizes, int n_in,
                              void* d_out, int out_size, void* d_ws, size_t ws_size,
                              hipStream_t stream){
    const float* atom  = (const float*)d_in[0];
    const float* nbr   = (const float*)d_in[1];
    const int*   adj   = (const int*)  d_in[2];
    const float* embW  = (const float*)d_in[3];
    const float* embB  = (const float*)d_in[4];
    const float* convW = (const float*)d_in[5];
    const float* convB = (const float*)d_in[6];
    const float* bn1g  = (const float*)d_in[7];
    const float* bn1b  = (const float*)d_in[8];
    const float* bn2g  = (const float*)d_in[9];
    const float* bn2b  = (const float*)d_in[10];
    const float* fcW   = (const float*)d_in[11];
    const float* fcb   = (const float*)d_in[12];
    const float* outW  = (const float*)d_in[13];
    const float* outb  = (const float*)d_in[14];
    float* out = (float*)d_out;
    float* ws  = (float*)d_ws;

    const int ROWS = N0c * NAt;            // 1536
    float* fea    = ws;                    // 98304
    float* p1     = ws + 98304;            // 196608
    float* p2     = ws + 294912;           // 196608
    float* summed = ws + 491520;           // 98304
    float* SRL    = ws + 589824;           // 3 * 12288
    float* ST     = ws + 626688;           // 125952
    float* cntf   = ws + 752640;           // 1536
    float* q3     = ws + 754176;           // 384
    float* W3T    = ws + 754560;           // 16896
    unsigned short* W3F = (unsigned short*)(ws + 771456);  // 24576 f
    const size_t PERS = 796032;

    size_t ws_f = ws_size / sizeof(float);
    int nblk; float *pG, *G; int compact = 0;
    if (ws_f >= PERS + (size_t)1536 * 1681 + 1681 + 64){
        nblk = 1536; pG = ws + PERS; G = pG + (size_t)nblk * 1681;
    } else if (ws_f >= PERS + (size_t)768 * 1681 + 1681 + 64){
        nblk = 768;  pG = ws + PERS; G = pG + (size_t)nblk * 1681;
    } else if (ws_f >= PERS + (size_t)384 * 1681 + 1681 + 64){
        nblk = 384;  pG = ws + PERS; G = pG + (size_t)nblk * 1681;
    } else {
        // compact overlay: pG over fea..SRL (dead until front l0); G inside
        // ST region — so ST must come from the separate k_pre AFTER k_prep
        // consumed G. Gram runs with doST=0 in this tier.
        nblk = 384;  pG = ws;        G = ws + 650000;  compact = 1;
    }
    int rpb = 1536 / nblk;
    int ph  = nblk / 96;

    // 1: gram (+ST/cnt fused unless compact; zeroes G from block 0)
    k_gram <<<nblk, 128, 0, stream>>>(nbr, adj, pG, ST, cntf, G, rpb,
                                      compact ? 0 : 1);
    // 2: reduce gram partials into G
    k_gred <<<27 * ph, 64, 0, stream>>>(pG, G);
    // 3: one-time weight prep (W3T + W3F + q3) + SRL zeroing (no memset)
    k_prep <<<NCc * 32, 320, 0, stream>>>(G, convW, W3T, W3F, q3, SRL);
    // 3b (compact tier only): ST/cnt via standalone pre (after G consumed)
    if (compact)
        k_pre <<<ROWS, 256, 0, stream>>>(nbr, adj, ST, cntf);

    for (int l = 0; l < NCc; ++l){
        const float* Wl   = convW + (size_t)l * 169 * C2;
        const float* bl   = convB + l * C2;
        const float* W3Tl = W3T + (size_t)l * C2 * 44;
        const unsigned short* W3Fl = W3F + (size_t)l * WFRAG;
        float* sum1R = SRL + l * SRL_STRIDE;
        float* sq1R  = sum1R + 4096;
        float* sum2R = sum1R + 8192;
        float* sq2R  = sum1R + 10240;
        const float* sum2Rp = (l > 0) ? SRL + (l - 1) * SRL_STRIDE + 8192 : SRL;
        const float* sq2Rp  = (l > 0) ? SRL + (l - 1) * SRL_STRIDE + 10240 : SRL;
        const float* g2p    = bn2g + (l > 0 ? (l - 1) : 0) * Fc;
        const float* b2p    = bn2b + (l > 0 ? (l - 1) : 0) * Fc;

        k_front <<<ROWS, 256, 0, stream>>>(fea, atom, embW, embB,
                                           Wl, bl, W3Tl, ST, cntf,
                                           p1, p2, sum1R, sq1R,
                                           summed, sum2Rp, sq2Rp, g2p, b2p,
                                           l > 0 ? 1 : 0);
        k_apply <<<ROWS, 512, 0, stream>>>(nbr, adj, W3Fl, p1, p2,
                                           sum1R, sq1R, q3 + l * C2,
                                           bn1g + l * C2, bn1b + l * C2,
                                           summed, sum2R, sq2R);
    }

    k_final<<<N0c, Hc, 0, stream>>>(fea, summed,
                                    SRL + 2 * SRL_STRIDE + 8192,
                                    SRL + 2 * SRL_STRIDE + 10240,
                                    bn2g + 2 * Fc, bn2b + 2 * Fc,
                                    fcW, fcb, outW, outb, out);
}

// Round 7
// 251.763 us; speedup vs baseline: 3.8519x; 1.0253x over previous
//
#include <hip/hip_runtime.h>
#include <math.h>

#define N0c   16
#define NAt   96
#define ORIG  92
#define Fc    64
#define Kc    41
#define Hc    128
#define NCc   3
#define C2    128   // 2F
#define EPSBN 1e-5f
#define JG    4
#define JPW   (NAt / JG)
#define NREP  32    // atomic replica slots
#define SRL_STRIDE 12288   // per-layer replica block
#define AROW  72    // k_apply LDS A row stride (ushorts)
#define NROWU (NAt * AROW)          // 6912 ushorts per plane per row
#define NBHF  ((size_t)1536 * 2 * NROWU / 2)   // nbh floats: 10,616,832
#define WFRAG 16384 // ushorts per layer in W3F (k_apply B frags)
#define INV1  (1.f / (float)(N0c * NAt * NAt))
#define INV2  (1.f / (float)(N0c * NAt))

typedef __attribute__((ext_vector_type(8))) short short8_t;   // 8 bf16
typedef __attribute__((ext_vector_type(4))) float f32x4;

__device__ __forceinline__ float sp_(float x){
    return fmaxf(x, 0.f) + __logf(1.f + __expf(-fabsf(x)));
}
__device__ __forceinline__ float sgm_(float x){
    return 1.f / (1.f + __expf(-x));
}
__device__ __forceinline__ unsigned short bfhi(float x){
    union { float f; unsigned u; } v; v.f = x;
    unsigned r = v.u + 0x7fff + ((v.u >> 16) & 1);   // RNE to bf16
    return (unsigned short)(r >> 16);
}
__device__ __forceinline__ float bf2f(unsigned short h){
    union { float f; unsigned u; } v; v.u = ((unsigned)h) << 16; return v.f;
}

// Compact-ws fallback only: S_r, T_r, cnt_r (identical to R15 k_pre).
__global__ __launch_bounds__(256) void k_pre(const float* __restrict__ nbr,
                                             const int*   __restrict__ adj,
                                             float* __restrict__ ST,
                                             float* __restrict__ cntf){
    int r    = blockIdx.x;
    int lane = threadIdx.x & 63;
    int jg   = __builtin_amdgcn_readfirstlane(threadIdx.x >> 6);
    __shared__ float rS[JG][Kc], rT[JG][Kc], rc[JG];
    float S = 0.f, T = 0.f, cn = 0.f;
    int j0 = jg * JPW;
    for (int j = j0; j < j0 + JPW; ++j){
        float a = (float)adj[r * NAt + j];
        float v = (lane < Kc) ? nbr[((size_t)r * NAt + j) * Kc + lane] : 0.f;
        S += v; T += a * v; cn += a;
    }
    if (lane < Kc){ rS[jg][lane] = S; rT[jg][lane] = T; }
    if (lane == 0) rc[jg] = cn;
    __syncthreads();
    int t = threadIdx.x;
    if (t < Kc){
        ST[r * (2 * Kc) + t]      = rS[0][t] + rS[1][t] + rS[2][t] + rS[3][t];
        ST[r * (2 * Kc) + Kc + t] = rT[0][t] + rT[1][t] + rT[2][t] + rT[3][t];
    }
    if (t == 0) cntf[r] = rc[0] + rc[1] + rc[2] + rc[3];
}

// Gram partials + (fused) S/T/cnt + G-zeroing (verified R13/R16 inner loop)
// + R7: doNBH writes the layer-invariant bf16 hi/lo split of each row in the
// padded AROW layout (pads pre-zeroed) so k_apply stages by pure copy x3.
__global__ __launch_bounds__(128) void k_gram(const float* __restrict__ nbr,
                                              const int*   __restrict__ adj,
                                              float* __restrict__ pG,
                                              float* __restrict__ ST,
                                              float* __restrict__ cntf,
                                              float* __restrict__ G,
                                              unsigned short* __restrict__ nbh,
                                              int rpb, int doST, int doNBH){
    int blk = blockIdx.x;
    int t   = threadIdx.x;
    int k   = (t % 21) * 2;
    int lb  = (t / 21) * 7;
    __shared__ float L[NAt * Kc];
    __shared__ float AJf[NAt];
    if (blk == 0){                                   // zero G (consumed by gred)
        for (int i = t; i < Kc * Kc; i += 128) G[i] = 0.f;
    }
    float a0[7] = {0,0,0,0,0,0,0}, a1[7] = {0,0,0,0,0,0,0};
    for (int rr = 0; rr < rpb; ++rr){
        int r = blk * rpb + rr;
        __syncthreads();
        for (int i = t; i < NAt * Kc; i += 128)
            L[i] = nbr[(size_t)r * NAt * Kc + i];
        if (t < NAt) AJf[t] = (float)adj[r * NAt + t];
        __syncthreads();
        if (doST && t < Kc){                         // S/T from LDS tile
            float S = 0.f, T = 0.f;
            for (int j = 0; j < NAt; ++j){
                float v = L[j * Kc + t];
                S += v; T += AJf[j] * v;
            }
            ST[r * (2 * Kc) + t]      = S;
            ST[r * (2 * Kc) + Kc + t] = T;
        }
        if (doST && t == Kc){
            float cn = 0.f;
            for (int j = 0; j < NAt; ++j) cn += AJf[j];
            cntf[r] = cn;
        }
        if (doNBH){                                  // hi/lo planes, AROW pad
            unsigned short* dst = nbh + (size_t)r * (2 * NROWU);
            for (int i = t; i < NROWU; i += 128){
                int j = i / AROW, kk = i - j * AROW;
                float x = (kk < Kc) ? L[j * Kc + kk] : 0.f;
                unsigned short hi = bfhi(x);
                dst[i]         = hi;
                dst[NROWU + i] = bfhi(x - bf2f(hi));
            }
        }
        if (t < 126){
            for (int j = 0; j < NAt; ++j){
                float vk0 = L[j * Kc + k];
                float vk1 = (k + 1 < Kc) ? L[j * Kc + k + 1] : 0.f;
                #pragma unroll
                for (int m = 0; m < 7; ++m){
                    if (lb + m < Kc){
                        float lv = L[j * Kc + lb + m];
                        a0[m] += vk0 * lv;
                        a1[m] += vk1 * lv;
                    }
                }
            }
        }
    }
    if (t < 126){
        float* dst = pG + (size_t)blk * (Kc * Kc);
        #pragma unroll
        for (int m = 0; m < 7; ++m){
            if (lb + m < Kc){
                dst[k * Kc + lb + m] = a0[m];
                if (k + 1 < Kc) dst[(k + 1) * Kc + lb + m] = a1[m];
            }
        }
    }
}

__global__ __launch_bounds__(64) void k_gred(const float* __restrict__ pG,
                                             float* __restrict__ G){
    int i  = (blockIdx.x % 27) * 64 + threadIdx.x;
    int b0 = (blockIdx.x / 27) * 96;
    if (i < Kc * Kc){
        float s = 0.f;
        #pragma unroll 4
        for (int b = b0; b < b0 + 96; ++b) s += pG[(size_t)b * (Kc * Kc) + i];
        atomicAdd(&G[i], s);
    }
}

// One-time prep, WIDE (R16-verified) + SRL zeroing (R6-verified).
__global__ __launch_bounds__(320) void k_prep(const float* __restrict__ G,
                                              const float* __restrict__ convW,
                                              float* __restrict__ W3T,
                                              unsigned short* __restrict__ W3F,
                                              float* __restrict__ q3,
                                              float* __restrict__ SRL){
    int bi   = blockIdx.x;
    int l    = bi >> 5;            // /32  -> layer
    int g    = bi & 31;            // group within layer
    int tid  = threadIdx.x;
    int lane = tid & 63;
    int w    = __builtin_amdgcn_readfirstlane(tid >> 6);   // 0..4
    const float* Wl = convW + (size_t)l * 169 * C2;
    __shared__ float GL[Kc * Kc];
    __shared__ float w3s[4][Kc];
    for (int i = tid; i < Kc * Kc; i += 320) GL[i] = G[i];

    // fold-in: zero stats replicas (was a separate hipMemsetAsync dispatch)
    for (int i = bi * 320 + tid; i < 3 * SRL_STRIDE; i += 96 * 320) SRL[i] = 0.f;

    int   c  = g * 4 + (w & 3);
    float w3 = 0.f;
    if (w < 4){
        w3 = (lane < Kc) ? Wl[(C2 + lane) * C2 + c] : 0.f;
        if (lane < 44)
            W3T[((size_t)l * C2 + c) * 44 + lane] = (lane < Kc) ? w3 : 0.f;
        if (lane < Kc) w3s[w][lane] = w3;
    }
    __syncthreads();

    if (w == 4){
        // W3F fragments: fid = g, 64 lanes of this wave
        int h  = g & 1;
        int ks = (g >> 1) & 1;
        int nt = g >> 2;
        int n  = nt * 16 + (lane & 15);
        unsigned short* dst = W3F + (size_t)l * WFRAG + g * 512 + lane * 8;
        #pragma unroll
        for (int i = 0; i < 8; ++i){
            int kk = ks * 32 + (lane >> 4) * 8 + i;
            float x = (kk < Kc) ? Wl[(C2 + kk) * C2 + n] : 0.f;
            unsigned short hi = bfhi(x);
            dst[i] = h ? bfhi(x - bf2f(hi)) : hi;
        }
    } else {
        float gw = 0.f;
        if (lane < Kc){
            #pragma unroll
            for (int m = 0; m < Kc; ++m) gw += GL[lane * Kc + m] * w3s[w][m];
        }
        float part = (lane < Kc) ? w3 * gw : 0.f;
        part += __shfl_xor(part, 1);
        part += __shfl_xor(part, 2);
        part += __shfl_xor(part, 4);
        part += __shfl_xor(part, 8);
        part += __shfl_xor(part, 16);
        part += __shfl_xor(part, 32);
        if (lane == 0) q3[l * C2 + c] = part;
    }
}

// Front (R15 v3 structure + embed fold; measured-best R1 variant).
__global__ __launch_bounds__(256)
void k_front(float* __restrict__ fea,
             const float* __restrict__ atom,
             const float* __restrict__ embW,
             const float* __restrict__ embB,
             const float* __restrict__ Wl,
             const float* __restrict__ bl,
             const float* __restrict__ W3Tl,
             const float* __restrict__ ST,
             const float* __restrict__ cntf,
             float* __restrict__ p1,
             float* __restrict__ p2,
             float* __restrict__ sum1R,
             float* __restrict__ sq1R,
             const float* __restrict__ summed,
             const float* __restrict__ sum2Rp,
             const float* __restrict__ sq2Rp,
             const float* __restrict__ g2p,
             const float* __restrict__ b2p,
             int upd){
    int r    = blockIdx.x;
    int tid  = threadIdx.x;
    int c    = tid & 127;
    int half = __builtin_amdgcn_readfirstlane(tid >> 7);
    __shared__ float F[Fc];
    __shared__ float A2L[Fc], B2L[Fc];
    __shared__ float P1h[C2], P2h[C2], TTs[C2];

    if (upd){
        if (tid < Fc){
            float s = 0.f, q = 0.f;
            for (int rr = 0; rr < NREP; ++rr){
                s += sum2Rp[rr * Fc + tid];
                q += sq2Rp[rr * Fc + tid];
            }
            float m = s * INV2;
            float v = q * INV2 - m * m;
            float A = g2p[tid] * rsqrtf(v + EPSBN);
            A2L[tid] = A;
            B2L[tid] = b2p[tid] - m * A;
        }
        __syncthreads();
        if (tid < Fc){
            float nv = sp_(fea[r * Fc + tid] + summed[r * Fc + tid] * A2L[tid] + B2L[tid]);
            F[tid] = nv;
            fea[r * Fc + tid] = nv;          // persist for next front / k_final
        }
        __syncthreads();
    } else {
        // l==0: embed inline (atom row is wave-uniform -> s_loads)
        if (tid < Fc){
            const float* ar = atom + r * ORIG;
            float acc = embB[tid];
            #pragma unroll 4
            for (int o = 0; o < ORIG; ++o) acc += ar[o] * embW[o * Fc + tid];
            F[tid] = acc;
            fea[r * Fc + tid] = acc;         // consumed by front l=1
        }
        __syncthreads();
    }

    // p12 partial over f in [half*32, half*32+32)
    float a1p = 0.f, a2p = 0.f;
    int f0 = half * 32;
    #pragma unroll 8
    for (int f = f0; f < f0 + 32; ++f){
        float fv = F[f];                     // LDS broadcast
        a1p += fv * Wl[f * C2 + c];
        a2p += fv * Wl[(Fc + f) * C2 + c];
    }
    // dot: half 0 -> u = S·w3 ; half 1 -> tt = T·w3 (uniform s_loads of S/T)
    const float* wt = W3Tl + c * 44;
    const float* Sr = ST + r * (2 * Kc) + half * Kc;
    float dot = 0.f;
    #pragma unroll
    for (int k = 0; k < 40; k += 4){
        float4 wv = *(const float4*)(wt + k);
        dot += Sr[k] * wv.x + Sr[k + 1] * wv.y + Sr[k + 2] * wv.z + Sr[k + 3] * wv.w;
    }
    dot += Sr[40] * wt[40];

    if (half == 1){ P1h[c] = a1p; P2h[c] = a2p; TTs[c] = dot; }
    __syncthreads();
    if (half == 0){
        float a1 = a1p + P1h[c] + bl[c];
        float a2 = a2p + P2h[c];
        float u  = dot;
        float tt = TTs[c];
        p1[r * C2 + c] = a1;
        p2[r * C2 + c] = a2;
        float cn = cntf[r];
        float s1 = (float)NAt * a1 + cn * a2 + u;
        float q1 = (float)NAt * a1 * a1 + cn * a2 * a2
                 + 2.f * cn * a1 * a2 + 2.f * a1 * u + 2.f * a2 * tt;
        int slot = blockIdx.x & (NREP - 1);
        atomicAdd(&sum1R[slot * C2 + c], s1);
        atomicAdd(&sq1R[slot * C2 + c], q1);
    }
}

// Pass 2 (MFMA, R13-verified math). useCache=1: stage pre-split hi/lo planes
// from nbh by coalesced uint4 copy (no div, no cvt, no pad loop — pads are
// pre-zeroed by k_gram). useCache=0: original float staging (fallback tiers).
__global__ __launch_bounds__(512)
void k_apply(const float* __restrict__ nbr,
             const int*   __restrict__ adj,
             const unsigned short* __restrict__ nbh,
             const unsigned short* __restrict__ W3Fl,
             const float* __restrict__ p1,
             const float* __restrict__ p2,
             const float* __restrict__ sum1R,
             const float* __restrict__ sq1R,
             const float* __restrict__ qv,
             const float* __restrict__ g1,
             const float* __restrict__ b1,
             float* __restrict__ summed,
             float* __restrict__ sum2R,
             float* __restrict__ sq2R,
             int useCache){
    int r    = blockIdx.x;
    int tid  = threadIdx.x;
    int lane = tid & 63;
    int w    = __builtin_amdgcn_readfirstlane(tid >> 6);
    int ntF  = w & 3;
    int mh   = w >> 2;

    __shared__ __align__(16) unsigned short sAH[NROWU];
    __shared__ __align__(16) unsigned short sAL[NROWU];
    __shared__ float AJ[NAt];
    __shared__ float PL1[C2], PL2[C2], A1L[C2], B1L[C2];
    __shared__ float TpW[8][16];

    short8_t BH[2][2], BL[2][2];
    #pragma unroll
    for (int ni = 0; ni < 2; ++ni){
        int nt = ntF + ni * 4;
        #pragma unroll
        for (int ks = 0; ks < 2; ++ks){
            int fidH = (nt * 2 + ks) * 2;
            BH[ni][ks] = *(const short8_t*)(W3Fl + fidH * 512 + lane * 8);
            BL[ni][ks] = *(const short8_t*)(W3Fl + (fidH + 1) * 512 + lane * 8);
        }
    }

    if (useCache){
        const uint4* src = (const uint4*)(nbh + (size_t)r * (2 * NROWU));
        uint4* dH = (uint4*)sAH;
        uint4* dL = (uint4*)sAL;
        #pragma unroll
        for (int i = 0; i < 2; ++i){                 // 864 = 512 + 352
            int idx = tid + i * 512;
            if (idx < NROWU / 8){
                dH[idx] = src[idx];
                dL[idx] = src[NROWU / 8 + idx];
            }
        }
    } else {
        const float* nb = nbr + (size_t)r * (NAt * Kc);
        for (int idx = tid; idx < NAt * Kc; idx += 512){
            int j = idx / Kc, k = idx - j * Kc;
            float x = nb[idx];
            unsigned short hi = bfhi(x);
            sAH[j * AROW + k] = hi;
            sAL[j * AROW + k] = bfhi(x - bf2f(hi));
        }
        for (int idx = tid; idx < NAt * 23; idx += 512){
            int j = idx / 23, k = Kc + (idx - j * 23);
            sAH[j * AROW + k] = 0;
            sAL[j * AROW + k] = 0;
        }
    }
    if (tid < C2){
        int c = tid;
        float s = 0.f, q = 0.f;
        for (int rr = 0; rr < NREP; ++rr){ s += sum1R[rr * C2 + c]; q += sq1R[rr * C2 + c]; }
        float m = s * INV1;
        float v = (q + qv[c]) * INV1 - m * m;
        float A = g1[c] * rsqrtf(v + EPSBN);
        A1L[c] = A;
        B1L[c] = b1[c] - m * A;
    } else if (tid < 256){
        PL1[tid - 128] = p1[r * C2 + tid - 128];
    } else if (tid < 384){
        PL2[tid - 256] = p2[r * C2 + tid - 256];
    } else if (tid < 480){
        AJ[tid - 384] = (float)adj[r * NAt + tid - 384];
    }
    __syncthreads();

    f32x4 acc[3][2] = {};
    int q4 = (lane >> 4) * 8;
    #pragma unroll
    for (int mt = 0; mt < 3; ++mt){
        int jrow = (mh * 48 + mt * 16 + (lane & 15)) * AROW;
        short8_t AH0 = *(const short8_t*)(&sAH[jrow + q4]);
        short8_t AH1 = *(const short8_t*)(&sAH[jrow + 32 + q4]);
        short8_t AL0 = *(const short8_t*)(&sAL[jrow + q4]);
        short8_t AL1 = *(const short8_t*)(&sAL[jrow + 32 + q4]);
        #pragma unroll
        for (int ni = 0; ni < 2; ++ni){
            acc[mt][ni] = __builtin_amdgcn_mfma_f32_16x16x32_bf16(AH0, BH[ni][0], acc[mt][ni], 0, 0, 0);
            acc[mt][ni] = __builtin_amdgcn_mfma_f32_16x16x32_bf16(AH0, BL[ni][0], acc[mt][ni], 0, 0, 0);
            acc[mt][ni] = __builtin_amdgcn_mfma_f32_16x16x32_bf16(AL0, BH[ni][0], acc[mt][ni], 0, 0, 0);
            acc[mt][ni] = __builtin_amdgcn_mfma_f32_16x16x32_bf16(AH1, BH[ni][1], acc[mt][ni], 0, 0, 0);
            acc[mt][ni] = __builtin_amdgcn_mfma_f32_16x16x32_bf16(AH1, BL[ni][1], acc[mt][ni], 0, 0, 0);
            acc[mt][ni] = __builtin_amdgcn_mfma_f32_16x16x32_bf16(AL1, BH[ni][1], acc[mt][ni], 0, 0, 0);
        }
    }

    int cF = ntF * 16 + (lane & 15);
    int cC = cF + 64;
    float p1F = PL1[cF], p2F = PL2[cF], A1F = A1L[cF], B1F = B1L[cF];
    float p1C = PL1[cC], p2C = PL2[cC], A1C = A1L[cC], B1C = B1L[cC];
    float tsum = 0.f;
    #pragma unroll
    for (int mt = 0; mt < 3; ++mt){
        #pragma unroll
        for (int rg = 0; rg < 4; ++rg){
            int j = mh * 48 + mt * 16 + (lane >> 4) * 4 + rg;
            float ajf = AJ[j];
            float gf = (p1F + ajf * p2F + acc[mt][0][rg]) * A1F + B1F;
            float gc = (p1C + ajf * p2C + acc[mt][1][rg]) * A1C + B1C;
            tsum += sgm_(gf) * sp_(gc);
        }
    }
    tsum += __shfl_xor(tsum, 16);
    tsum += __shfl_xor(tsum, 32);
    if (lane < 16) TpW[w][lane] = tsum;
    __syncthreads();
    if (tid < Fc){
        int f = tid;
        float s = TpW[f >> 4][f & 15] + TpW[(f >> 4) + 4][f & 15];
        summed[r * Fc + f] = s;
        int slot = blockIdx.x & (NREP - 1);
        atomicAdd(&sum2R[slot * Fc + f], s);
        atomicAdd(&sq2R[slot * Fc + f], s * s);
    }
}

// Tail (identical to R13).
__global__ __launch_bounds__(128) void k_final(const float* __restrict__ fea,
                                               const float* __restrict__ summed,
                                               const float* __restrict__ sum2R,
                                               const float* __restrict__ sq2R,
                                               const float* __restrict__ g2,
                                               const float* __restrict__ b2,
                                               const float* __restrict__ fcW,
                                               const float* __restrict__ fcb,
                                               const float* __restrict__ outW,
                                               const float* __restrict__ outb,
                                               float* __restrict__ out){
    int b = blockIdx.x;
    int t = threadIdx.x;
    __shared__ float spc[Fc];
    __shared__ float red[Hc];
    if (t < Fc){
        float s = 0.f, q = 0.f;
        for (int r = 0; r < NREP; ++r){ s += sum2R[r * Fc + t]; q += sq2R[r * Fc + t]; }
        float m  = s * INV2;
        float v  = q * INV2 - m * m;
        float A2 = g2[t] * rsqrtf(v + EPSBN);
        float B2 = b2[t] - m * A2;
        float acc = 0.f;
        for (int i = 0; i < NAt; ++i){
            int idx = (b * NAt + i) * Fc + t;
            acc += sp_(fea[idx] + summed[idx] * A2 + B2);
        }
        spc[t] = sp_(acc * (1.f / NAt));
    }
    __syncthreads();
    float h = fcb[t];
    #pragma unroll 4
    for (int f = 0; f < Fc; ++f) h += spc[f] * fcW[f * Hc + t];
    h = sp_(h);
    red[t] = h * outW[t];
    __syncthreads();
    for (int off = 64; off > 0; off >>= 1){
        if (t < off) red[t] += red[t + off];
        __syncthreads();
    }
    if (t == 0) out[b] = red[0] + outb[0];
}

extern "C" void kernel_launch(void* const* d_in, const int* in_sizes, int n_in,
                              void* d_out, int out_size, void* d_ws, size_t ws_size,
                              hipStream_t stream){
    const float* atom  = (const float*)d_in[0];
    const float* nbr   = (const float*)d_in[1];
    const int*   adj   = (const int*)  d_in[2];
    const float* embW  = (const float*)d_in[3];
    const float* embB  = (const float*)d_in[4];
    const float* convW = (const float*)d_in[5];
    const float* convB = (const float*)d_in[6];
    const float* bn1g  = (const float*)d_in[7];
    const float* bn1b  = (const float*)d_in[8];
    const float* bn2g  = (const float*)d_in[9];
    const float* bn2b  = (const float*)d_in[10];
    const float* fcW   = (const float*)d_in[11];
    const float* fcb   = (const float*)d_in[12];
    const float* outW  = (const float*)d_in[13];
    const float* outb  = (const float*)d_in[14];
    float* out = (float*)d_out;
    float* ws  = (float*)d_ws;

    const int ROWS = N0c * NAt;            // 1536
    float* fea    = ws;                    // 98304
    float* p1     = ws + 98304;            // 196608
    float* p2     = ws + 294912;           // 196608
    float* summed = ws + 491520;           // 98304
    float* SRL    = ws + 589824;           // 3 * 12288
    float* ST     = ws + 626688;           // 125952
    float* cntf   = ws + 752640;           // 1536
    float* q3     = ws + 754176;           // 384
    float* W3T    = ws + 754560;           // 16896
    unsigned short* W3F = (unsigned short*)(ws + 771456);  // 24576 f
    const size_t PERS = 796032;

    size_t ws_f = ws_size / sizeof(float);
    unsigned short* nbh = (unsigned short*)(ws + PERS);    // 10,616,832 f when cached
    int nblk; float *pG, *G; int compact = 0; int cache = 0;
    if (ws_f >= PERS + NBHF + (size_t)1536 * 1681 + 1681 + 64){
        cache = 1; nblk = 1536; pG = ws + PERS + NBHF; G = pG + (size_t)nblk * 1681;
    } else if (ws_f >= PERS + NBHF + (size_t)768 * 1681 + 1681 + 64){
        cache = 1; nblk = 768;  pG = ws + PERS + NBHF; G = pG + (size_t)nblk * 1681;
    } else if (ws_f >= PERS + NBHF + (size_t)384 * 1681 + 1681 + 64){
        cache = 1; nblk = 384;  pG = ws + PERS + NBHF; G = pG + (size_t)nblk * 1681;
    } else if (ws_f >= PERS + (size_t)384 * 1681 + 1681 + 64){
        cache = 0; nblk = 384;  pG = ws + PERS;        G = pG + (size_t)nblk * 1681;
    } else {
        // compact overlay: pG over fea..SRL (dead until front l0); G inside
        // ST region — ST then comes from the separate k_pre AFTER k_prep.
        cache = 0; nblk = 384;  pG = ws;  G = ws + 650000;  compact = 1;
    }
    int rpb = 1536 / nblk;
    int ph  = nblk / 96;

    // 1: gram (+ST/cnt fused unless compact; +nbh split when cached)
    k_gram <<<nblk, 128, 0, stream>>>(nbr, adj, pG, ST, cntf, G, nbh, rpb,
                                      compact ? 0 : 1, cache);
    // 2: reduce gram partials into G
    k_gred <<<27 * ph, 64, 0, stream>>>(pG, G);
    // 3: one-time weight prep (W3T + W3F + q3) + SRL zeroing (no memset)
    k_prep <<<NCc * 32, 320, 0, stream>>>(G, convW, W3T, W3F, q3, SRL);
    // 3b (compact tier only): ST/cnt via standalone pre (after G consumed)
    if (compact)
        k_pre <<<ROWS, 256, 0, stream>>>(nbr, adj, ST, cntf);

    for (int l = 0; l < NCc; ++l){
        const float* Wl   = convW + (size_t)l * 169 * C2;
        const float* bl   = convB + l * C2;
        const float* W3Tl = W3T + (size_t)l * C2 * 44;
        const unsigned short* W3Fl = W3F + (size_t)l * WFRAG;
        float* sum1R = SRL + l * SRL_STRIDE;
        float* sq1R  = sum1R + 4096;
        float* sum2R = sum1R + 8192;
        float* sq2R  = sum1R + 10240;
        const float* sum2Rp = (l > 0) ? SRL + (l - 1) * SRL_STRIDE + 8192 : SRL;
        const float* sq2Rp  = (l > 0) ? SRL + (l - 1) * SRL_STRIDE + 10240 : SRL;
        const float* g2p    = bn2g + (l > 0 ? (l - 1) : 0) * Fc;
        const float* b2p    = bn2b + (l > 0 ? (l - 1) : 0) * Fc;

        k_front <<<ROWS, 256, 0, stream>>>(fea, atom, embW, embB,
                                           Wl, bl, W3Tl, ST, cntf,
                                           p1, p2, sum1R, sq1R,
                                           summed, sum2Rp, sq2Rp, g2p, b2p,
                                           l > 0 ? 1 : 0);
        k_apply <<<ROWS, 512, 0, stream>>>(nbr, adj, nbh, W3Fl, p1, p2,
                                           sum1R, sq1R, q3 + l * C2,
                                           bn1g + l * C2, bn1b + l * C2,
                                           summed, sum2R, sq2R, cache);
    }

    k_final<<<N0c, Hc, 0, stream>>>(fea, summed,
                                    SRL + 2 * SRL_STRIDE + 8192,
                                    SRL + 2 * SRL_STRIDE + 10240,
                                    bn2g + 2 * Fc, bn2b + 2 * Fc,
                                    fcW, fcb, outW, outb, out);
}

// Round 8
// 249.554 us; speedup vs baseline: 3.8860x; 1.0088x over previous
//
#include <hip/hip_runtime.h>
#include <math.h>

#define N0c   16
#define NAt   96
#define ORIG  92
#define Fc    64
#define Kc    41
#define Hc    128
#define NCc   3
#define C2    128   // 2F
#define EPSBN 1e-5f
#define JG    4
#define JPW   (NAt / JG)
#define NREP  32    // atomic replica slots
#define SRL_STRIDE 12288   // per-layer replica block
#define AROW  72    // k_apply LDS A row stride (ushorts)
#define NROWU (NAt * AROW)          // 6912 ushorts per plane per row
#define NBHF  ((size_t)1536 * 2 * NROWU / 2)   // nbh floats: 10,616,832
#define WFRAG 16384 // ushorts per layer in W3F (k_apply B frags)
#define LST   42    // k_gram padded LDS row stride (floats)
#define INV1  (1.f / (float)(N0c * NAt * NAt))
#define INV2  (1.f / (float)(N0c * NAt))

typedef __attribute__((ext_vector_type(8))) short short8_t;   // 8 bf16
typedef __attribute__((ext_vector_type(4))) float f32x4;

__device__ __forceinline__ float sp_(float x){
    return fmaxf(x, 0.f) + __logf(1.f + __expf(-fabsf(x)));
}
__device__ __forceinline__ float sgm_(float x){
    return 1.f / (1.f + __expf(-x));
}
__device__ __forceinline__ unsigned short bfhi(float x){
    union { float f; unsigned u; } v; v.f = x;
    unsigned r = v.u + 0x7fff + ((v.u >> 16) & 1);   // RNE to bf16
    return (unsigned short)(r >> 16);
}
__device__ __forceinline__ float bf2f(unsigned short h){
    union { float f; unsigned u; } v; v.u = ((unsigned)h) << 16; return v.f;
}

// Compact-ws fallback only: S_r, T_r, cnt_r (identical to R15 k_pre).
__global__ __launch_bounds__(256) void k_pre(const float* __restrict__ nbr,
                                             const int*   __restrict__ adj,
                                             float* __restrict__ ST,
                                             float* __restrict__ cntf){
    int r    = blockIdx.x;
    int lane = threadIdx.x & 63;
    int jg   = __builtin_amdgcn_readfirstlane(threadIdx.x >> 6);
    __shared__ float rS[JG][Kc], rT[JG][Kc], rc[JG];
    float S = 0.f, T = 0.f, cn = 0.f;
    int j0 = jg * JPW;
    for (int j = j0; j < j0 + JPW; ++j){
        float a = (float)adj[r * NAt + j];
        float v = (lane < Kc) ? nbr[((size_t)r * NAt + j) * Kc + lane] : 0.f;
        S += v; T += a * v; cn += a;
    }
    if (lane < Kc){ rS[jg][lane] = S; rT[jg][lane] = T; }
    if (lane == 0) rc[jg] = cn;
    __syncthreads();
    int t = threadIdx.x;
    if (t < Kc){
        ST[r * (2 * Kc) + t]      = rS[0][t] + rS[1][t] + rS[2][t] + rS[3][t];
        ST[r * (2 * Kc) + Kc + t] = rT[0][t] + rT[1][t] + rT[2][t] + rT[3][t];
    }
    if (t == 0) cntf[r] = rc[0] + rc[1] + rc[2] + rc[3];
}

// Gram + fused S/T/cnt + nbh split. R8: 6x6 output tile per thread (49
// threads, one wave), stride-42 LDS so each j-iter is 6 aligned float2
// reads (same-address broadcast across lanes -> conflict-free) instead of
// 9 scalar b32 — halves LDS-port pressure (the measured bottleneck).
// Each G element still gets exactly one FMA per j, in j-order -> G is
// bit-identical to the R7 kernel. pG layout unchanged (k*41+l).
__global__ __launch_bounds__(128) void k_gram(const float* __restrict__ nbr,
                                              const int*   __restrict__ adj,
                                              float* __restrict__ pG,
                                              float* __restrict__ ST,
                                              float* __restrict__ cntf,
                                              float* __restrict__ G,
                                              unsigned short* __restrict__ nbh,
                                              int rpb, int doST, int doNBH){
    int blk = blockIdx.x;
    int t   = threadIdx.x;
    __shared__ float L2[NAt * LST];
    __shared__ float AJf[NAt];
    if (blk == 0){                                   // zero G (consumed by gred)
        for (int i = t; i < Kc * Kc; i += 128) G[i] = 0.f;
    }
    int k0 = (t % 7) * 6;          // gram tile origin (t < 49)
    int l0 = (t / 7) * 6;
    float acc[6][6] = {};
    for (int rr = 0; rr < rpb; ++rr){
        int r = blk * rpb + rr;
        __syncthreads();
        {   // stage: coalesced read, padded write (incremental div 41)
            const float* src = nbr + (size_t)r * (NAt * Kc);
            int idx = t, j = t / Kc, k = t - j * Kc;
            while (idx < NAt * Kc){
                L2[j * LST + k] = src[idx];
                idx += 128; j += 3; k += 5;
                if (k >= Kc){ k -= Kc; ++j; }
            }
        }
        if (t < NAt){
            L2[t * LST + Kc] = 0.f;                  // zero pad col 41
            AJf[t] = (float)adj[r * NAt + t];
        }
        __syncthreads();
        if (doST && t < Kc){                         // S/T from LDS tile
            float S = 0.f, T = 0.f;
            for (int j = 0; j < NAt; ++j){
                float v = L2[j * LST + t];
                S += v; T += AJf[j] * v;
            }
            ST[r * (2 * Kc) + t]      = S;
            ST[r * (2 * Kc) + Kc + t] = T;
        }
        if (doST && t == Kc){
            float cn = 0.f;
            for (int j = 0; j < NAt; ++j) cn += AJf[j];
            cntf[r] = cn;
        }
        if (doNBH){                                  // hi/lo planes, AROW pad
            unsigned short* dst = nbh + (size_t)r * (2 * NROWU);
            for (int i = t; i < NROWU; i += 128){
                int j = i / AROW, kk = i - j * AROW;
                float x = (kk < Kc) ? L2[j * LST + kk] : 0.f;
                unsigned short hi = bfhi(x);
                dst[i]         = hi;
                dst[NROWU + i] = bfhi(x - bf2f(hi));
            }
        }
        if (t < 49){
            for (int j = 0; j < NAt; ++j){
                const float2* pk = (const float2*)&L2[j * LST + k0];
                const float2* pl = (const float2*)&L2[j * LST + l0];
                float2 ka = pk[0], kb = pk[1], kc = pk[2];
                float2 la = pl[0], lb = pl[1], lc = pl[2];
                float kv[6] = { ka.x, ka.y, kb.x, kb.y, kc.x, kc.y };
                float lv[6] = { la.x, la.y, lb.x, lb.y, lc.x, lc.y };
                #pragma unroll
                for (int a = 0; a < 6; ++a)
                    #pragma unroll
                    for (int b = 0; b < 6; ++b)
                        acc[a][b] += kv[a] * lv[b];
            }
        }
    }
    if (t < 49){
        float* dst = pG + (size_t)blk * (Kc * Kc);
        #pragma unroll
        for (int a = 0; a < 6; ++a){
            if (k0 + a < Kc){
                #pragma unroll
                for (int b = 0; b < 6; ++b)
                    if (l0 + b < Kc)
                        dst[(k0 + a) * Kc + l0 + b] = acc[a][b];
            }
        }
    }
}

__global__ __launch_bounds__(64) void k_gred(const float* __restrict__ pG,
                                             float* __restrict__ G){
    int i  = (blockIdx.x % 27) * 64 + threadIdx.x;
    int b0 = (blockIdx.x / 27) * 96;
    if (i < Kc * Kc){
        float s = 0.f;
        #pragma unroll 4
        for (int b = b0; b < b0 + 96; ++b) s += pG[(size_t)b * (Kc * Kc) + i];
        atomicAdd(&G[i], s);
    }
}

// One-time prep, WIDE (R16-verified) + SRL zeroing (R6-verified).
__global__ __launch_bounds__(320) void k_prep(const float* __restrict__ G,
                                              const float* __restrict__ convW,
                                              float* __restrict__ W3T,
                                              unsigned short* __restrict__ W3F,
                                              float* __restrict__ q3,
                                              float* __restrict__ SRL){
    int bi   = blockIdx.x;
    int l    = bi >> 5;            // /32  -> layer
    int g    = bi & 31;            // group within layer
    int tid  = threadIdx.x;
    int lane = tid & 63;
    int w    = __builtin_amdgcn_readfirstlane(tid >> 6);   // 0..4
    const float* Wl = convW + (size_t)l * 169 * C2;
    __shared__ float GL[Kc * Kc];
    __shared__ float w3s[4][Kc];
    for (int i = tid; i < Kc * Kc; i += 320) GL[i] = G[i];

    // fold-in: zero stats replicas (was a separate hipMemsetAsync dispatch)
    for (int i = bi * 320 + tid; i < 3 * SRL_STRIDE; i += 96 * 320) SRL[i] = 0.f;

    int   c  = g * 4 + (w & 3);
    float w3 = 0.f;
    if (w < 4){
        w3 = (lane < Kc) ? Wl[(C2 + lane) * C2 + c] : 0.f;
        if (lane < 44)
            W3T[((size_t)l * C2 + c) * 44 + lane] = (lane < Kc) ? w3 : 0.f;
        if (lane < Kc) w3s[w][lane] = w3;
    }
    __syncthreads();

    if (w == 4){
        // W3F fragments: fid = g, 64 lanes of this wave
        int h  = g & 1;
        int ks = (g >> 1) & 1;
        int nt = g >> 2;
        int n  = nt * 16 + (lane & 15);
        unsigned short* dst = W3F + (size_t)l * WFRAG + g * 512 + lane * 8;
        #pragma unroll
        for (int i = 0; i < 8; ++i){
            int kk = ks * 32 + (lane >> 4) * 8 + i;
            float x = (kk < Kc) ? Wl[(C2 + kk) * C2 + n] : 0.f;
            unsigned short hi = bfhi(x);
            dst[i] = h ? bfhi(x - bf2f(hi)) : hi;
        }
    } else {
        float gw = 0.f;
        if (lane < Kc){
            #pragma unroll
            for (int m = 0; m < Kc; ++m) gw += GL[lane * Kc + m] * w3s[w][m];
        }
        float part = (lane < Kc) ? w3 * gw : 0.f;
        part += __shfl_xor(part, 1);
        part += __shfl_xor(part, 2);
        part += __shfl_xor(part, 4);
        part += __shfl_xor(part, 8);
        part += __shfl_xor(part, 16);
        part += __shfl_xor(part, 32);
        if (lane == 0) q3[l * C2 + c] = part;
    }
}

// Front (R15 v3 structure + embed fold; measured-best R1 variant).
__global__ __launch_bounds__(256)
void k_front(float* __restrict__ fea,
             const float* __restrict__ atom,
             const float* __restrict__ embW,
             const float* __restrict__ embB,
             const float* __restrict__ Wl,
             const float* __restrict__ bl,
             const float* __restrict__ W3Tl,
             const float* __restrict__ ST,
             const float* __restrict__ cntf,
             float* __restrict__ p1,
             float* __restrict__ p2,
             float* __restrict__ sum1R,
             float* __restrict__ sq1R,
             const float* __restrict__ summed,
             const float* __restrict__ sum2Rp,
             const float* __restrict__ sq2Rp,
             const float* __restrict__ g2p,
             const float* __restrict__ b2p,
             int upd){
    int r    = blockIdx.x;
    int tid  = threadIdx.x;
    int c    = tid & 127;
    int half = __builtin_amdgcn_readfirstlane(tid >> 7);
    __shared__ float F[Fc];
    __shared__ float A2L[Fc], B2L[Fc];
    __shared__ float P1h[C2], P2h[C2], TTs[C2];

    if (upd){
        if (tid < Fc){
            float s = 0.f, q = 0.f;
            for (int rr = 0; rr < NREP; ++rr){
                s += sum2Rp[rr * Fc + tid];
                q += sq2Rp[rr * Fc + tid];
            }
            float m = s * INV2;
            float v = q * INV2 - m * m;
            float A = g2p[tid] * rsqrtf(v + EPSBN);
            A2L[tid] = A;
            B2L[tid] = b2p[tid] - m * A;
        }
        __syncthreads();
        if (tid < Fc){
            float nv = sp_(fea[r * Fc + tid] + summed[r * Fc + tid] * A2L[tid] + B2L[tid]);
            F[tid] = nv;
            fea[r * Fc + tid] = nv;          // persist for next front / k_final
        }
        __syncthreads();
    } else {
        // l==0: embed inline (atom row is wave-uniform -> s_loads)
        if (tid < Fc){
            const float* ar = atom + r * ORIG;
            float acc = embB[tid];
            #pragma unroll 4
            for (int o = 0; o < ORIG; ++o) acc += ar[o] * embW[o * Fc + tid];
            F[tid] = acc;
            fea[r * Fc + tid] = acc;         // consumed by front l=1
        }
        __syncthreads();
    }

    // p12 partial over f in [half*32, half*32+32)
    float a1p = 0.f, a2p = 0.f;
    int f0 = half * 32;
    #pragma unroll 8
    for (int f = f0; f < f0 + 32; ++f){
        float fv = F[f];                     // LDS broadcast
        a1p += fv * Wl[f * C2 + c];
        a2p += fv * Wl[(Fc + f) * C2 + c];
    }
    // dot: half 0 -> u = S·w3 ; half 1 -> tt = T·w3 (uniform s_loads of S/T)
    const float* wt = W3Tl + c * 44;
    const float* Sr = ST + r * (2 * Kc) + half * Kc;
    float dot = 0.f;
    #pragma unroll
    for (int k = 0; k < 40; k += 4){
        float4 wv = *(const float4*)(wt + k);
        dot += Sr[k] * wv.x + Sr[k + 1] * wv.y + Sr[k + 2] * wv.z + Sr[k + 3] * wv.w;
    }
    dot += Sr[40] * wt[40];

    if (half == 1){ P1h[c] = a1p; P2h[c] = a2p; TTs[c] = dot; }
    __syncthreads();
    if (half == 0){
        float a1 = a1p + P1h[c] + bl[c];
        float a2 = a2p + P2h[c];
        float u  = dot;
        float tt = TTs[c];
        p1[r * C2 + c] = a1;
        p2[r * C2 + c] = a2;
        float cn = cntf[r];
        float s1 = (float)NAt * a1 + cn * a2 + u;
        float q1 = (float)NAt * a1 * a1 + cn * a2 * a2
                 + 2.f * cn * a1 * a2 + 2.f * a1 * u + 2.f * a2 * tt;
        int slot = blockIdx.x & (NREP - 1);
        atomicAdd(&sum1R[slot * C2 + c], s1);
        atomicAdd(&sq1R[slot * C2 + c], q1);
    }
}

// Pass 2 (MFMA, R13-verified math). useCache=1: stage pre-split hi/lo planes
// from nbh by coalesced uint4 copy (no div, no cvt, no pad loop — pads are
// pre-zeroed by k_gram). useCache=0: original float staging (fallback tiers).
__global__ __launch_bounds__(512)
void k_apply(const float* __restrict__ nbr,
             const int*   __restrict__ adj,
             const unsigned short* __restrict__ nbh,
             const unsigned short* __restrict__ W3Fl,
             const float* __restrict__ p1,
             const float* __restrict__ p2,
             const float* __restrict__ sum1R,
             const float* __restrict__ sq1R,
             const float* __restrict__ qv,
             const float* __restrict__ g1,
             const float* __restrict__ b1,
             float* __restrict__ summed,
             float* __restrict__ sum2R,
             float* __restrict__ sq2R,
             int useCache){
    int r    = blockIdx.x;
    int tid  = threadIdx.x;
    int lane = tid & 63;
    int w    = __builtin_amdgcn_readfirstlane(tid >> 6);
    int ntF  = w & 3;
    int mh   = w >> 2;

    __shared__ __align__(16) unsigned short sAH[NROWU];
    __shared__ __align__(16) unsigned short sAL[NROWU];
    __shared__ float AJ[NAt];
    __shared__ float PL1[C2], PL2[C2], A1L[C2], B1L[C2];
    __shared__ float TpW[8][16];

    short8_t BH[2][2], BL[2][2];
    #pragma unroll
    for (int ni = 0; ni < 2; ++ni){
        int nt = ntF + ni * 4;
        #pragma unroll
        for (int ks = 0; ks < 2; ++ks){
            int fidH = (nt * 2 + ks) * 2;
            BH[ni][ks] = *(const short8_t*)(W3Fl + fidH * 512 + lane * 8);
            BL[ni][ks] = *(const short8_t*)(W3Fl + (fidH + 1) * 512 + lane * 8);
        }
    }

    if (useCache){
        const uint4* src = (const uint4*)(nbh + (size_t)r * (2 * NROWU));
        uint4* dH = (uint4*)sAH;
        uint4* dL = (uint4*)sAL;
        #pragma unroll
        for (int i = 0; i < 2; ++i){                 // 864 = 512 + 352
            int idx = tid + i * 512;
            if (idx < NROWU / 8){
                dH[idx] = src[idx];
                dL[idx] = src[NROWU / 8 + idx];
            }
        }
    } else {
        const float* nb = nbr + (size_t)r * (NAt * Kc);
        for (int idx = tid; idx < NAt * Kc; idx += 512){
            int j = idx / Kc, k = idx - j * Kc;
            float x = nb[idx];
            unsigned short hi = bfhi(x);
            sAH[j * AROW + k] = hi;
            sAL[j * AROW + k] = bfhi(x - bf2f(hi));
        }
        for (int idx = tid; idx < NAt * 23; idx += 512){
            int j = idx / 23, k = Kc + (idx - j * 23);
            sAH[j * AROW + k] = 0;
            sAL[j * AROW + k] = 0;
        }
    }
    if (tid < C2){
        int c = tid;
        float s = 0.f, q = 0.f;
        for (int rr = 0; rr < NREP; ++rr){ s += sum1R[rr * C2 + c]; q += sq1R[rr * C2 + c]; }
        float m = s * INV1;
        float v = (q + qv[c]) * INV1 - m * m;
        float A = g1[c] * rsqrtf(v + EPSBN);
        A1L[c] = A;
        B1L[c] = b1[c] - m * A;
    } else if (tid < 256){
        PL1[tid - 128] = p1[r * C2 + tid - 128];
    } else if (tid < 384){
        PL2[tid - 256] = p2[r * C2 + tid - 256];
    } else if (tid < 480){
        AJ[tid - 384] = (float)adj[r * NAt + tid - 384];
    }
    __syncthreads();

    f32x4 acc[3][2] = {};
    int q4 = (lane >> 4) * 8;
    #pragma unroll
    for (int mt = 0; mt < 3; ++mt){
        int jrow = (mh * 48 + mt * 16 + (lane & 15)) * AROW;
        short8_t AH0 = *(const short8_t*)(&sAH[jrow + q4]);
        short8_t AH1 = *(const short8_t*)(&sAH[jrow + 32 + q4]);
        short8_t AL0 = *(const short8_t*)(&sAL[jrow + q4]);
        short8_t AL1 = *(const short8_t*)(&sAL[jrow + 32 + q4]);
        #pragma unroll
        for (int ni = 0; ni < 2; ++ni){
            acc[mt][ni] = __builtin_amdgcn_mfma_f32_16x16x32_bf16(AH0, BH[ni][0], acc[mt][ni], 0, 0, 0);
            acc[mt][ni] = __builtin_amdgcn_mfma_f32_16x16x32_bf16(AH0, BL[ni][0], acc[mt][ni], 0, 0, 0);
            acc[mt][ni] = __builtin_amdgcn_mfma_f32_16x16x32_bf16(AL0, BH[ni][0], acc[mt][ni], 0, 0, 0);
            acc[mt][ni] = __builtin_amdgcn_mfma_f32_16x16x32_bf16(AH1, BH[ni][1], acc[mt][ni], 0, 0, 0);
            acc[mt][ni] = __builtin_amdgcn_mfma_f32_16x16x32_bf16(AH1, BL[ni][1], acc[mt][ni], 0, 0, 0);
            acc[mt][ni] = __builtin_amdgcn_mfma_f32_16x16x32_bf16(AL1, BH[ni][1], acc[mt][ni], 0, 0, 0);
        }
    }

    int cF = ntF * 16 + (lane & 15);
    int cC = cF + 64;
    float p1F = PL1[cF], p2F = PL2[cF], A1F = A1L[cF], B1F = B1L[cF];
    float p1C = PL1[cC], p2C = PL2[cC], A1C = A1L[cC], B1C = B1L[cC];
    float tsum = 0.f;
    #pragma unroll
    for (int mt = 0; mt < 3; ++mt){
        #pragma unroll
        for (int rg = 0; rg < 4; ++rg){
            int j = mh * 48 + mt * 16 + (lane >> 4) * 4 + rg;
            float ajf = AJ[j];
            float gf = (p1F + ajf * p2F + acc[mt][0][rg]) * A1F + B1F;
            float gc = (p1C + ajf * p2C + acc[mt][1][rg]) * A1C + B1C;
            tsum += sgm_(gf) * sp_(gc);
        }
    }
    tsum += __shfl_xor(tsum, 16);
    tsum += __shfl_xor(tsum, 32);
    if (lane < 16) TpW[w][lane] = tsum;
    __syncthreads();
    if (tid < Fc){
        int f = tid;
        float s = TpW[f >> 4][f & 15] + TpW[(f >> 4) + 4][f & 15];
        summed[r * Fc + f] = s;
        int slot = blockIdx.x & (NREP - 1);
        atomicAdd(&sum2R[slot * Fc + f], s);
        atomicAdd(&sq2R[slot * Fc + f], s * s);
    }
}

// Tail (identical to R13).
__global__ __launch_bounds__(128) void k_final(const float* __restrict__ fea,
                                               const float* __restrict__ summed,
                                               const float* __restrict__ sum2R,
                                               const float* __restrict__ sq2R,
                                               const float* __restrict__ g2,
                                               const float* __restrict__ b2,
                                               const float* __restrict__ fcW,
                                               const float* __restrict__ fcb,
                                               const float* __restrict__ outW,
                                               const float* __restrict__ outb,
                                               float* __restrict__ out){
    int b = blockIdx.x;
    int t = threadIdx.x;
    __shared__ float spc[Fc];
    __shared__ float red[Hc];
    if (t < Fc){
        float s = 0.f, q = 0.f;
        for (int r = 0; r < NREP; ++r){ s += sum2R[r * Fc + t]; q += sq2R[r * Fc + t]; }
        float m  = s * INV2;
        float v  = q * INV2 - m * m;
        float A2 = g2[t] * rsqrtf(v + EPSBN);
        float B2 = b2[t] - m * A2;
        float acc = 0.f;
        for (int i = 0; i < NAt; ++i){
            int idx = (b * NAt + i) * Fc + t;
            acc += sp_(fea[idx] + summed[idx] * A2 + B2);
        }
        spc[t] = sp_(acc * (1.f / NAt));
    }
    __syncthreads();
    float h = fcb[t];
    #pragma unroll 4
    for (int f = 0; f < Fc; ++f) h += spc[f] * fcW[f * Hc + t];
    h = sp_(h);
    red[t] = h * outW[t];
    __syncthreads();
    for (int off = 64; off > 0; off >>= 1){
        if (t < off) red[t] += red[t + off];
        __syncthreads();
    }
    if (t == 0) out[b] = red[0] + outb[0];
}

extern "C" void kernel_launch(void* const* d_in, const int* in_sizes, int n_in,
                              void* d_out, int out_size, void* d_ws, size_t ws_size,
                              hipStream_t stream){
    const float* atom  = (const float*)d_in[0];
    const float* nbr   = (const float*)d_in[1];
    const int*   adj   = (const int*)  d_in[2];
    const float* embW  = (const float*)d_in[3];
    const float* embB  = (const float*)d_in[4];
    const float* convW = (const float*)d_in[5];
    const float* convB = (const float*)d_in[6];
    const float* bn1g  = (const float*)d_in[7];
    const float* bn1b  = (const float*)d_in[8];
    const float* bn2g  = (const float*)d_in[9];
    const float* bn2b  = (const float*)d_in[10];
    const float* fcW   = (const float*)d_in[11];
    const float* fcb   = (const float*)d_in[12];
    const float* outW  = (const float*)d_in[13];
    const float* outb  = (const float*)d_in[14];
    float* out = (float*)d_out;
    float* ws  = (float*)d_ws;

    const int ROWS = N0c * NAt;            // 1536
    float* fea    = ws;                    // 98304
    float* p1     = ws + 98304;            // 196608
    float* p2     = ws + 294912;           // 196608
    float* summed = ws + 491520;           // 98304
    float* SRL    = ws + 589824;           // 3 * 12288
    float* ST     = ws + 626688;           // 125952
    float* cntf   = ws + 752640;           // 1536
    float* q3     = ws + 754176;           // 384
    float* W3T    = ws + 754560;           // 16896
    unsigned short* W3F = (unsigned short*)(ws + 771456);  // 24576 f
    const size_t PERS = 796032;

    size_t ws_f = ws_size / sizeof(float);
    unsigned short* nbh = (unsigned short*)(ws + PERS);    // 10,616,832 f when cached
    int nblk; float *pG, *G; int compact = 0; int cache = 0;
    if (ws_f >= PERS + NBHF + (size_t)1536 * 1681 + 1681 + 64){
        cache = 1; nblk = 1536; pG = ws + PERS + NBHF; G = pG + (size_t)nblk * 1681;
    } else if (ws_f >= PERS + NBHF + (size_t)768 * 1681 + 1681 + 64){
        cache = 1; nblk = 768;  pG = ws + PERS + NBHF; G = pG + (size_t)nblk * 1681;
    } else if (ws_f >= PERS + NBHF + (size_t)384 * 1681 + 1681 + 64){
        cache = 1; nblk = 384;  pG = ws + PERS + NBHF; G = pG + (size_t)nblk * 1681;
    } else if (ws_f >= PERS + (size_t)384 * 1681 + 1681 + 64){
        cache = 0; nblk = 384;  pG = ws + PERS;        G = pG + (size_t)nblk * 1681;
    } else {
        // compact overlay: pG over fea..SRL (dead until front l0); G inside
        // ST region — ST then comes from the separate k_pre AFTER k_prep.
        cache = 0; nblk = 384;  pG = ws;  G = ws + 650000;  compact = 1;
    }
    int rpb = 1536 / nblk;
    int ph  = nblk / 96;

    // 1: gram (+ST/cnt fused unless compact; +nbh split when cached)
    k_gram <<<nblk, 128, 0, stream>>>(nbr, adj, pG, ST, cntf, G, nbh, rpb,
                                      compact ? 0 : 1, cache);
    // 2: reduce gram partials into G
    k_gred <<<27 * ph, 64, 0, stream>>>(pG, G);
    // 3: one-time weight prep (W3T + W3F + q3) + SRL zeroing (no memset)
    k_prep <<<NCc * 32, 320, 0, stream>>>(G, convW, W3T, W3F, q3, SRL);
    // 3b (compact tier only): ST/cnt via standalone pre (after G consumed)
    if (compact)
        k_pre <<<ROWS, 256, 0, stream>>>(nbr, adj, ST, cntf);

    for (int l = 0; l < NCc; ++l){
        const float* Wl   = convW + (size_t)l * 169 * C2;
        const float* bl   = convB + l * C2;
        const float* W3Tl = W3T + (size_t)l * C2 * 44;
        const unsigned short* W3Fl = W3F + (size_t)l * WFRAG;
        float* sum1R = SRL + l * SRL_STRIDE;
        float* sq1R  = sum1R + 4096;
        float* sum2R = sum1R + 8192;
        float* sq2R  = sum1R + 10240;
        const float* sum2Rp = (l > 0) ? SRL + (l - 1) * SRL_STRIDE + 8192 : SRL;
        const float* sq2Rp  = (l > 0) ? SRL + (l - 1) * SRL_STRIDE + 10240 : SRL;
        const float* g2p    = bn2g + (l > 0 ? (l - 1) : 0) * Fc;
        const float* b2p    = bn2b + (l > 0 ? (l - 1) : 0) * Fc;

        k_front <<<ROWS, 256, 0, stream>>>(fea, atom, embW, embB,
                                           Wl, bl, W3Tl, ST, cntf,
                                           p1, p2, sum1R, sq1R,
                                           summed, sum2Rp, sq2Rp, g2p, b2p,
                                           l > 0 ? 1 : 0);
        k_apply <<<ROWS, 512, 0, stream>>>(nbr, adj, nbh, W3Fl, p1, p2,
                                           sum1R, sq1R, q3 + l * C2,
                                           bn1g + l * C2, bn1b + l * C2,
                                           summed, sum2R, sq2R, cache);
    }

    k_final<<<N0c, Hc, 0, stream>>>(fea, summed,
                                    SRL + 2 * SRL_STRIDE + 8192,
                                    SRL + 2 * SRL_STRIDE + 10240,
                                    bn2g + 2 * Fc, bn2b + 2 * Fc,
                                    fcW, fcb, outW, outb, out);
}